// Round 1
// baseline (1850.679 us; speedup 1.0000x reference)
//
#include <hip/hip_runtime.h>

// ---------------------------------------------------------------------------
// Autoencoder: x+embed -> Linear(2048,1536)+GELU -> Linear(1536,256) -> top4
//              -> softmax -> mix components(256,3) -> Linear(3,1536)+GELU
//              -> Linear(1536,2048). Outputs: encoded (broadcast components),
//              decoded.
// Strategy: encoder GEMMs in split-bf16 (3-product MFMA, fp32-class accuracy)
// so the top-4 selection matches the fp32/fp64 reference; borderline rows
// (gap < TAU) re-done exactly in fp64. Decoder GEMM in plain bf16 MFMA.
// ---------------------------------------------------------------------------

typedef float  f32x4  __attribute__((ext_vector_type(4)));
typedef short  short8 __attribute__((ext_vector_type(8)));

#define DEVINL __device__ __forceinline__

constexpr int  NB      = 16384;          // batch
constexpr int  IN_DIM  = 2048;
constexpr int  HID     = 1536;
constexpr int  NC      = 256;
constexpr long ENC_ELEMS = (long)NB * NC * 3;   // 12582912 floats (output 0)
constexpr float TAU = 2e-5f;             // rescue margin (~6 sigma of logit err)

DEVINL unsigned short f2bf(float f) {    // fp32 -> bf16 bits, RNE
  unsigned int u = __builtin_bit_cast(unsigned int, f);
  u = u + 0x7fffu + ((u >> 16) & 1u);
  return (unsigned short)(u >> 16);
}
DEVINL float bf2f(unsigned short h) {
  unsigned int u = ((unsigned int)h) << 16;
  return __builtin_bit_cast(float, u);
}
DEVINL float gelu_f(float v) {
  return 0.5f * v * (1.0f + erff(v * 0.70710678118654752440f));
}
DEVINL void llds16(const void* g, void* l) {   // async global->LDS, 16B/lane
  __builtin_amdgcn_global_load_lds(
      (const __attribute__((address_space(1))) void*)g,
      (__attribute__((address_space(3))) void*)l, 16, 0, 0);
}
DEVINL f32x4 mfma_bf16(short8 a, short8 b, f32x4 c) {
  return __builtin_amdgcn_mfma_f32_16x16x32_bf16(a, b, c, 0, 0, 0);
}

// ---------------------------------------------------------------------------
// Transpose (K,N) fp32 -> (N,K) bf16 hi (+ optional lo) for B operands.
// ---------------------------------------------------------------------------
__global__ __launch_bounds__(256) void transpose_split_kernel(
    const float* __restrict__ in, int K, int N,
    unsigned short* __restrict__ outH, unsigned short* __restrict__ outL)
{
  __shared__ float t[32][33];
  int tx = threadIdx.x & 31, ty = threadIdx.x >> 5;   // 32 x 8
  int n0 = blockIdx.x * 32, k0 = blockIdx.y * 32;
#pragma unroll
  for (int i = 0; i < 4; ++i)
    t[ty + i * 8][tx] = in[(long)(k0 + ty + i * 8) * N + n0 + tx];
  __syncthreads();
#pragma unroll
  for (int i = 0; i < 4; ++i) {
    float f = t[tx][ty + i * 8];
    long  o = (long)(n0 + ty + i * 8) * K + k0 + tx;
    unsigned short hb = f2bf(f);
    outH[o] = hb;
    if (outL) outL[o] = f2bf(f - bf2f(hb));
  }
}

// ---------------------------------------------------------------------------
// GEMM: C[M,N] = act(A[M,K] * B^T[N,K] + bias). 128x128 tile, 4 waves,
// 16x16x32 bf16 MFMA. SPLIT: A staged fp32, split hi/lo in-register;
// B pre-split (hi+lo) -> 3 MFMAs per fragment. EMBED: add embed row to A.
// ---------------------------------------------------------------------------
template<bool SPLIT, bool EMBED, bool GELU>
__global__ __launch_bounds__(256) void gemm_kernel(
    const float* __restrict__ Af, const unsigned short* __restrict__ Ab, long lda,
    const unsigned short* __restrict__ BhT, const unsigned short* __restrict__ BlT,
    long ldb, const float* __restrict__ bias, float* __restrict__ C, long ldc,
    int K, int nbn, const float* __restrict__ embedMat, const int* __restrict__ liPtr)
{
  constexpr int BM = 128, BN = 128, BK = 32;
  __shared__ alignas(16) float          sAf[SPLIT ? BM * BK : 8];
  __shared__ alignas(16) unsigned short sAb[SPLIT ? 8 : BM * BK];
  __shared__ alignas(16) unsigned short sBh[BN * BK];
  __shared__ alignas(16) unsigned short sBl[SPLIT ? BN * BK : 8];
  __shared__ alignas(16) float          sEmb[EMBED ? IN_DIM : 4];
  __shared__ float sBias[BN];

  int tid = threadIdx.x;
  // XCD-aware swizzle (grid counts all divisible by 8)
  int nwg = gridDim.x, q = nwg >> 3, b0 = blockIdx.x;
  int sw = (b0 & 7) * q + (b0 >> 3);
  int bm = sw / nbn, bn = sw % nbn;

  if constexpr (EMBED) {
    int li = liPtr[0];
    const f32x4* er = (const f32x4*)(embedMat + (long)li * IN_DIM);
    for (int i = tid; i < IN_DIM / 4; i += 256) ((f32x4*)sEmb)[i] = er[i];
  }
  if (tid < BN) sBias[tid] = bias[bn * BN + tid];

  int wid = tid >> 6, lane = tid & 63;
  int wm = wid >> 1, wn = wid & 1;
  int l15 = lane & 15, kq = lane >> 4;
  int koff = kq * 8;

  f32x4 acc[4][4] = {};

  int nk = K / BK;
  for (int kt = 0; kt < nk; ++kt) {
    __syncthreads();
    if constexpr (SPLIT) {
      const float* gA = Af + (long)(bm * BM + (tid >> 3)) * lda + kt * BK + (tid & 7) * 4;
#pragma unroll
      for (int j = 0; j < 4; ++j)
        llds16(gA + (long)(j * 32) * lda, (char*)sAf + j * 4096 + tid * 16);
    } else {
      const unsigned short* gA = Ab + (long)(bm * BM + (tid >> 2)) * lda + kt * BK + (tid & 3) * 8;
#pragma unroll
      for (int j = 0; j < 2; ++j)
        llds16(gA + (long)(j * 64) * lda, (char*)sAb + j * 4096 + tid * 16);
    }
    {
      const unsigned short* gB = BhT + (long)(bn * BN + (tid >> 2)) * ldb + kt * BK + (tid & 3) * 8;
#pragma unroll
      for (int j = 0; j < 2; ++j)
        llds16(gB + (long)(j * 64) * ldb, (char*)sBh + j * 4096 + tid * 16);
    }
    if constexpr (SPLIT) {
      const unsigned short* gL = BlT + (long)(bn * BN + (tid >> 2)) * ldb + kt * BK + (tid & 3) * 8;
#pragma unroll
      for (int j = 0; j < 2; ++j)
        llds16(gL + (long)(j * 64) * ldb, (char*)sBl + j * 4096 + tid * 16);
    }
    __syncthreads();

    short8 bh[4], bl[4];
#pragma unroll
    for (int n = 0; n < 4; ++n) {
      int col = wn * 64 + n * 16 + l15;
      bh[n] = *(const short8*)&sBh[col * BK + koff];
      if constexpr (SPLIT) bl[n] = *(const short8*)&sBl[col * BK + koff];
    }

    if constexpr (SPLIT) {
      float e[8];
      if constexpr (EMBED) {
#pragma unroll
        for (int i = 0; i < 8; ++i) e[i] = sEmb[kt * BK + koff + i];
      }
#pragma unroll
      for (int m = 0; m < 4; ++m) {
        int row = wm * 64 + m * 16 + l15;
        const float* ap = &sAf[row * BK + koff];
        short8 ah, al;
#pragma unroll
        for (int i = 0; i < 8; ++i) {
          float f = ap[i];
          if constexpr (EMBED) f += e[i];
          unsigned short hb = f2bf(f);
          float lo = f - bf2f(hb);
          ah[i] = (short)hb;
          al[i] = (short)f2bf(lo);
        }
#pragma unroll
        for (int n = 0; n < 4; ++n) {
          acc[m][n] = mfma_bf16(ah, bh[n], acc[m][n]);
          acc[m][n] = mfma_bf16(ah, bl[n], acc[m][n]);
          acc[m][n] = mfma_bf16(al, bh[n], acc[m][n]);
        }
      }
    } else {
#pragma unroll
      for (int m = 0; m < 4; ++m) {
        int row = wm * 64 + m * 16 + l15;
        short8 ah = *(const short8*)&sAb[row * BK + koff];
#pragma unroll
        for (int n = 0; n < 4; ++n)
          acc[m][n] = mfma_bf16(ah, bh[n], acc[m][n]);
      }
    }
  }

  // epilogue: C/D layout col = lane&15, row = (lane>>4)*4 + r
#pragma unroll
  for (int m = 0; m < 4; ++m) {
#pragma unroll
    for (int n = 0; n < 4; ++n) {
      int  gcol = bn * BN + wn * 64 + n * 16 + l15;
      float bb  = sBias[wn * 64 + n * 16 + l15];
#pragma unroll
      for (int r = 0; r < 4; ++r) {
        long grow = (long)bm * BM + wm * 64 + m * 16 + kq * 4 + r;
        float v = acc[m][n][r] + bb;
        if constexpr (GELU) v = gelu_f(v);
        C[grow * ldc + gcol] = v;
      }
    }
  }
}

// ---------------------------------------------------------------------------
// Per-row top-4 (+5th for margin), softmax, mix components -> pts.
// One wave per row; tie-break = lower index (matches jax.lax.top_k).
// ---------------------------------------------------------------------------
__global__ __launch_bounds__(256) void topk_kernel(
    const float* __restrict__ logits, const float* __restrict__ comp,
    float* __restrict__ pts, int* __restrict__ rescueCnt, int* __restrict__ rescueList)
{
  int wid = threadIdx.x >> 6, lane = threadIdx.x & 63;
  long row = (long)blockIdx.x * 4 + wid;
  f32x4 v4 = *(const f32x4*)(logits + row * NC + lane * 4);
  float a[4] = {v4[0], v4[1], v4[2], v4[3]};

  float tv[5]; int ti[5];
#pragma unroll
  for (int t = 0; t < 5; ++t) {
    float lv = a[0]; int li = lane * 4;
#pragma unroll
    for (int i = 1; i < 4; ++i)
      if (a[i] > lv) { lv = a[i]; li = lane * 4 + i; }
#pragma unroll
    for (int off = 32; off >= 1; off >>= 1) {
      float ov = __shfl_xor(lv, off);
      int   oi = __shfl_xor(li, off);
      if (ov > lv || (ov == lv && oi < li)) { lv = ov; li = oi; }
    }
    tv[t] = lv; ti[t] = li;
    if (t < 4 && (li >> 2) == lane) a[li & 3] = -INFINITY;
  }

  float m = tv[0], w[4], s = 0.f;
#pragma unroll
  for (int t = 0; t < 4; ++t) { w[t] = expf(tv[t] - m); s += w[t]; }
  float inv = 1.0f / s;
  if (lane < 3) {
    float p = 0.f;
#pragma unroll
    for (int t = 0; t < 4; ++t) p += w[t] * inv * comp[ti[t] * 3 + lane];
    pts[row * 3 + lane] = p;
  }
  if (lane == 0 && (tv[3] - tv[4]) < TAU) {
    int pos = atomicAdd(rescueCnt, 1);
    rescueList[pos] = (int)row;
  }
}

// ---------------------------------------------------------------------------
// Exact fp64 recompute of ambiguous rows (one block per row).
// ---------------------------------------------------------------------------
__global__ __launch_bounds__(256) void rescue_kernel(
    const float* __restrict__ x, const float* __restrict__ embedMat,
    const int* __restrict__ liPtr, const float* __restrict__ W1,
    const float* __restrict__ b1, const float* __restrict__ W2,
    const float* __restrict__ b2, const float* __restrict__ comp,
    float* __restrict__ pts, const int* __restrict__ cnt, const int* __restrict__ list)
{
  __shared__ double xd[IN_DIM];
  __shared__ double hd[HID];
  __shared__ double ld[NC];
  int tid = threadIdx.x;
  int li = liPtr[0];
  int n = *cnt;
  for (int it = blockIdx.x; it < n; it += gridDim.x) {
    int row = list[it];
    const float* xr = x + (long)row * IN_DIM;
    const float* er = embedMat + (long)li * IN_DIM;
    for (int j = tid; j < IN_DIM; j += 256)
      xd[j] = (double)xr[j] + (double)er[j];
    __syncthreads();
    for (int c = tid; c < HID; c += 256) {
      double s0 = 0, s1 = 0, s2 = 0, s3 = 0;
      const float* wp = W1 + c;
      for (int k = 0; k < IN_DIM; k += 4) {
        s0 += xd[k]     * (double)wp[(long)k * HID];
        s1 += xd[k + 1] * (double)wp[(long)(k + 1) * HID];
        s2 += xd[k + 2] * (double)wp[(long)(k + 2) * HID];
        s3 += xd[k + 3] * (double)wp[(long)(k + 3) * HID];
      }
      double s = (double)b1[c] + ((s0 + s1) + (s2 + s3));
      hd[c] = 0.5 * s * (1.0 + erf(s * 0.70710678118654752440));
    }
    __syncthreads();
    {
      int c = tid;   // 256 threads == NC
      double s0 = 0, s1 = 0, s2 = 0, s3 = 0;
      const float* wp = W2 + c;
      for (int k = 0; k < HID; k += 4) {
        s0 += hd[k]     * (double)wp[(long)k * NC];
        s1 += hd[k + 1] * (double)wp[(long)(k + 1) * NC];
        s2 += hd[k + 2] * (double)wp[(long)(k + 2) * NC];
        s3 += hd[k + 3] * (double)wp[(long)(k + 3) * NC];
      }
      ld[c] = (double)b2[c] + ((s0 + s1) + (s2 + s3));
    }
    __syncthreads();
    if (tid == 0) {
      int idx[4]; double val[4];
      unsigned long long mask[4] = {0, 0, 0, 0};
      for (int t = 0; t < 4; ++t) {
        double bv = -1e300; int bi = 0;
        for (int j = 0; j < NC; ++j) {
          if ((mask[j >> 6] >> (j & 63)) & 1ull) continue;
          if (ld[j] > bv) { bv = ld[j]; bi = j; }
        }
        idx[t] = bi; val[t] = bv; mask[bi >> 6] |= 1ull << (bi & 63);
      }
      double m = val[0], w[4], s = 0;
      for (int t = 0; t < 4; ++t) { w[t] = exp(val[t] - m); s += w[t]; }
      for (int c = 0; c < 3; ++c) {
        double p = 0;
        for (int t = 0; t < 4; ++t) p += (w[t] / s) * (double)comp[idx[t] * 3 + c];
        pts[(long)row * 3 + c] = (float)p;
      }
    }
    __syncthreads();
  }
}

// ---------------------------------------------------------------------------
// d = gelu(pts @ dec_w1 + dec_b1), stored bf16 (decoder GEMM A operand).
// ---------------------------------------------------------------------------
__global__ __launch_bounds__(256) void dec_a_kernel(
    const float* __restrict__ pts, const float* __restrict__ W1d,
    const float* __restrict__ b1d, unsigned short* __restrict__ dout)
{
  int  j = (blockIdx.x % 6) * 256 + threadIdx.x;
  long b = blockIdx.x / 6;
  const float* p = pts + b * 3;
  float s = fmaf(p[0], W1d[j], fmaf(p[1], W1d[HID + j], fmaf(p[2], W1d[2 * HID + j], b1d[j])));
  dout[b * HID + j] = f2bf(gelu_f(s));
}

// encoded output = components broadcast to (B, 256, 3)
__global__ __launch_bounds__(256) void enc_out_kernel(
    const float* __restrict__ comp, float* __restrict__ out)
{
  long base = (long)blockIdx.x * 768;
  int  t = threadIdx.x;
  out[base + t]       = comp[t];
  out[base + 256 + t] = comp[256 + t];
  out[base + 512 + t] = comp[512 + t];
}

__global__ void zero_cnt_kernel(int* c) { if (threadIdx.x == 0) *c = 0; }

// ---------------------------------------------------------------------------
extern "C" void kernel_launch(void* const* d_in, const int* in_sizes, int n_in,
                              void* d_out, int out_size, void* d_ws, size_t ws_size,
                              hipStream_t stream) {
  const float* x     = (const float*)d_in[0];
  const int*   liPtr = (const int*)  d_in[1];
  const float* embed = (const float*)d_in[2];
  const float* W1    = (const float*)d_in[3];
  const float* b1    = (const float*)d_in[4];
  const float* W2    = (const float*)d_in[5];
  const float* b2    = (const float*)d_in[6];
  const float* comp  = (const float*)d_in[7];
  const float* W1d   = (const float*)d_in[8];
  const float* b1d   = (const float*)d_in[9];
  const float* W2d   = (const float*)d_in[10];
  const float* b2d   = (const float*)d_in[11];
  float* out = (float*)d_out;

  char* w = (char*)d_ws;
  unsigned short* W1hT = (unsigned short*)(w);                      // 1536x2048 bf16
  unsigned short* W1lT = (unsigned short*)(w + 6291456);
  unsigned short* W2hT = (unsigned short*)(w + 12582912);           // 256x1536
  unsigned short* W2lT = (unsigned short*)(w + 13369344);
  unsigned short* W2dT = (unsigned short*)(w + 14155776);           // 2048x1536
  float* h      = (float*)(w + 20447232);                           // 16384x1536 f32
  float* logits = (float*)(w + 121110528);                          // 16384x256 f32
  float* pts    = (float*)(w + 137887744);                          // 16384x3
  int*   cnt    = (int*)  (w + 138084352);
  int*   list   = (int*)  (w + 138084608);
  unsigned short* dbuf = (unsigned short*)h;                        // reuse h region

  zero_cnt_kernel<<<1, 64, 0, stream>>>(cnt);
  transpose_split_kernel<<<dim3(HID / 32, IN_DIM / 32), 256, 0, stream>>>(W1, IN_DIM, HID, W1hT, W1lT);
  transpose_split_kernel<<<dim3(NC / 32, HID / 32),     256, 0, stream>>>(W2, HID, NC, W2hT, W2lT);
  transpose_split_kernel<<<dim3(IN_DIM / 32, HID / 32), 256, 0, stream>>>(W2d, HID, IN_DIM, W2dT, nullptr);

  // enc1: h = gelu((x+embed) @ W1 + b1)   [split-bf16, fp32-class]
  gemm_kernel<true, true, true><<<(NB / 128) * (HID / 128), 256, 0, stream>>>(
      x, nullptr, IN_DIM, W1hT, W1lT, IN_DIM, b1, h, HID, IN_DIM, HID / 128, embed, liPtr);
  // enc2: logits = h @ W2 + b2            [split-bf16]
  gemm_kernel<true, false, false><<<(NB / 128) * (NC / 128), 256, 0, stream>>>(
      h, nullptr, HID, W2hT, W2lT, HID, b2, logits, NC, HID, NC / 128, nullptr, nullptr);

  topk_kernel<<<NB / 4, 256, 0, stream>>>(logits, comp, pts, cnt, list);
  rescue_kernel<<<256, 256, 0, stream>>>(x, embed, liPtr, W1, b1, W2, b2, comp, pts, cnt, list);

  dec_a_kernel<<<NB * (HID / 256), 256, 0, stream>>>(pts, W1d, b1d, dbuf);
  // dec2: decoded = d @ W2d + b2d         [plain bf16]
  gemm_kernel<false, false, false><<<(NB / 128) * (IN_DIM / 128), 256, 0, stream>>>(
      nullptr, dbuf, HID, W2dT, nullptr, HID, b2d, out + ENC_ELEMS, IN_DIM, HID, IN_DIM / 128, nullptr, nullptr);

  enc_out_kernel<<<NB, 256, 0, stream>>>(comp, out);
}

// Round 2
// 844.122 us; speedup vs baseline: 2.1924x; 2.1924x over previous
//
#include <hip/hip_runtime.h>

// ---------------------------------------------------------------------------
// Autoencoder: x+embed -> Linear(2048,1536)+GELU -> Linear(1536,256) -> top4
//              -> softmax -> mix components(256,3) -> Linear(3,1536)+GELU
//              -> Linear(1536,2048). Outputs: encoded (broadcast components),
//              decoded.
// Strategy: encoder GEMMs in split-bf16 (3-product MFMA, fp32-class accuracy)
// so the top-4 selection matches the fp32/fp64 reference; borderline rows
// (gap < TAU) re-done exactly in fp64 via a PARALLEL 3-stage rescue pipeline
// (round-1 lesson: serial per-row rescue was 78% of runtime at 0.6% occupancy).
// Decoder GEMM in plain bf16 MFMA.
// ---------------------------------------------------------------------------

typedef float  f32x4  __attribute__((ext_vector_type(4)));
typedef short  short8 __attribute__((ext_vector_type(8)));

#define DEVINL __device__ __forceinline__

constexpr int  NB      = 16384;          // batch
constexpr int  IN_DIM  = 2048;
constexpr int  HID     = 1536;
constexpr int  NC      = 256;
constexpr long ENC_ELEMS = (long)NB * NC * 3;   // 12582912 floats (output 0)
constexpr float TAU = 2e-5f;             // rescue margin (~6 sigma of logit err)
constexpr int  MAXR = 64;                // fast-path rescue capacity (n~4 expected)

DEVINL unsigned short f2bf(float f) {    // fp32 -> bf16 bits, RNE
  unsigned int u = __builtin_bit_cast(unsigned int, f);
  u = u + 0x7fffu + ((u >> 16) & 1u);
  return (unsigned short)(u >> 16);
}
DEVINL float bf2f(unsigned short h) {
  unsigned int u = ((unsigned int)h) << 16;
  return __builtin_bit_cast(float, u);
}
DEVINL float gelu_f(float v) {
  return 0.5f * v * (1.0f + erff(v * 0.70710678118654752440f));
}
DEVINL void llds16(const void* g, void* l) {   // async global->LDS, 16B/lane
  __builtin_amdgcn_global_load_lds(
      (const __attribute__((address_space(1))) void*)g,
      (__attribute__((address_space(3))) void*)l, 16, 0, 0);
}
DEVINL f32x4 mfma_bf16(short8 a, short8 b, f32x4 c) {
  return __builtin_amdgcn_mfma_f32_16x16x32_bf16(a, b, c, 0, 0, 0);
}

// ---------------------------------------------------------------------------
// Transpose (K,N) fp32 -> (N,K) bf16 hi (+ optional lo) for B operands.
// ---------------------------------------------------------------------------
__global__ __launch_bounds__(256) void transpose_split_kernel(
    const float* __restrict__ in, int K, int N,
    unsigned short* __restrict__ outH, unsigned short* __restrict__ outL)
{
  __shared__ float t[32][33];
  int tx = threadIdx.x & 31, ty = threadIdx.x >> 5;   // 32 x 8
  int n0 = blockIdx.x * 32, k0 = blockIdx.y * 32;
#pragma unroll
  for (int i = 0; i < 4; ++i)
    t[ty + i * 8][tx] = in[(long)(k0 + ty + i * 8) * N + n0 + tx];
  __syncthreads();
#pragma unroll
  for (int i = 0; i < 4; ++i) {
    float f = t[tx][ty + i * 8];
    long  o = (long)(n0 + ty + i * 8) * K + k0 + tx;
    unsigned short hb = f2bf(f);
    outH[o] = hb;
    if (outL) outL[o] = f2bf(f - bf2f(hb));
  }
}

// ---------------------------------------------------------------------------
// GEMM: C[M,N] = act(A[M,K] * B^T[N,K] + bias). 128x128 tile, 4 waves,
// 16x16x32 bf16 MFMA. SPLIT: A staged fp32, split hi/lo in-register;
// B pre-split (hi+lo) -> 3 MFMAs per fragment. EMBED: add embed row to A.
// ---------------------------------------------------------------------------
template<bool SPLIT, bool EMBED, bool GELU>
__global__ __launch_bounds__(256) void gemm_kernel(
    const float* __restrict__ Af, const unsigned short* __restrict__ Ab, long lda,
    const unsigned short* __restrict__ BhT, const unsigned short* __restrict__ BlT,
    long ldb, const float* __restrict__ bias, float* __restrict__ C, long ldc,
    int K, int nbn, const float* __restrict__ embedMat, const int* __restrict__ liPtr)
{
  constexpr int BM = 128, BN = 128, BK = 32;
  __shared__ alignas(16) float          sAf[SPLIT ? BM * BK : 8];
  __shared__ alignas(16) unsigned short sAb[SPLIT ? 8 : BM * BK];
  __shared__ alignas(16) unsigned short sBh[BN * BK];
  __shared__ alignas(16) unsigned short sBl[SPLIT ? BN * BK : 8];
  __shared__ alignas(16) float          sEmb[EMBED ? IN_DIM : 4];
  __shared__ float sBias[BN];

  int tid = threadIdx.x;
  // XCD-aware swizzle (grid counts all divisible by 8)
  int nwg = gridDim.x, q = nwg >> 3, b0 = blockIdx.x;
  int sw = (b0 & 7) * q + (b0 >> 3);
  int bm = sw / nbn, bn = sw % nbn;

  if constexpr (EMBED) {
    int li = liPtr[0];
    const f32x4* er = (const f32x4*)(embedMat + (long)li * IN_DIM);
    for (int i = tid; i < IN_DIM / 4; i += 256) ((f32x4*)sEmb)[i] = er[i];
  }
  if (tid < BN) sBias[tid] = bias[bn * BN + tid];

  int wid = tid >> 6, lane = tid & 63;
  int wm = wid >> 1, wn = wid & 1;
  int l15 = lane & 15, kq = lane >> 4;
  int koff = kq * 8;

  f32x4 acc[4][4] = {};

  int nk = K / BK;
  for (int kt = 0; kt < nk; ++kt) {
    __syncthreads();
    if constexpr (SPLIT) {
      const float* gA = Af + (long)(bm * BM + (tid >> 3)) * lda + kt * BK + (tid & 7) * 4;
#pragma unroll
      for (int j = 0; j < 4; ++j)
        llds16(gA + (long)(j * 32) * lda, (char*)sAf + j * 4096 + tid * 16);
    } else {
      const unsigned short* gA = Ab + (long)(bm * BM + (tid >> 2)) * lda + kt * BK + (tid & 3) * 8;
#pragma unroll
      for (int j = 0; j < 2; ++j)
        llds16(gA + (long)(j * 64) * lda, (char*)sAb + j * 4096 + tid * 16);
    }
    {
      const unsigned short* gB = BhT + (long)(bn * BN + (tid >> 2)) * ldb + kt * BK + (tid & 3) * 8;
#pragma unroll
      for (int j = 0; j < 2; ++j)
        llds16(gB + (long)(j * 64) * ldb, (char*)sBh + j * 4096 + tid * 16);
    }
    if constexpr (SPLIT) {
      const unsigned short* gL = BlT + (long)(bn * BN + (tid >> 2)) * ldb + kt * BK + (tid & 3) * 8;
#pragma unroll
      for (int j = 0; j < 2; ++j)
        llds16(gL + (long)(j * 64) * ldb, (char*)sBl + j * 4096 + tid * 16);
    }
    __syncthreads();

    short8 bh[4], bl[4];
#pragma unroll
    for (int n = 0; n < 4; ++n) {
      int col = wn * 64 + n * 16 + l15;
      bh[n] = *(const short8*)&sBh[col * BK + koff];
      if constexpr (SPLIT) bl[n] = *(const short8*)&sBl[col * BK + koff];
    }

    if constexpr (SPLIT) {
      float e[8];
      if constexpr (EMBED) {
#pragma unroll
        for (int i = 0; i < 8; ++i) e[i] = sEmb[kt * BK + koff + i];
      }
#pragma unroll
      for (int m = 0; m < 4; ++m) {
        int row = wm * 64 + m * 16 + l15;
        const float* ap = &sAf[row * BK + koff];
        short8 ah, al;
#pragma unroll
        for (int i = 0; i < 8; ++i) {
          float f = ap[i];
          if constexpr (EMBED) f += e[i];
          unsigned short hb = f2bf(f);
          float lo = f - bf2f(hb);
          ah[i] = (short)hb;
          al[i] = (short)f2bf(lo);
        }
#pragma unroll
        for (int n = 0; n < 4; ++n) {
          acc[m][n] = mfma_bf16(ah, bh[n], acc[m][n]);
          acc[m][n] = mfma_bf16(ah, bl[n], acc[m][n]);
          acc[m][n] = mfma_bf16(al, bh[n], acc[m][n]);
        }
      }
    } else {
#pragma unroll
      for (int m = 0; m < 4; ++m) {
        int row = wm * 64 + m * 16 + l15;
        short8 ah = *(const short8*)&sAb[row * BK + koff];
#pragma unroll
        for (int n = 0; n < 4; ++n)
          acc[m][n] = mfma_bf16(ah, bh[n], acc[m][n]);
      }
    }
  }

  // epilogue: C/D layout col = lane&15, row = (lane>>4)*4 + r
#pragma unroll
  for (int m = 0; m < 4; ++m) {
#pragma unroll
    for (int n = 0; n < 4; ++n) {
      int  gcol = bn * BN + wn * 64 + n * 16 + l15;
      float bb  = sBias[wn * 64 + n * 16 + l15];
#pragma unroll
      for (int r = 0; r < 4; ++r) {
        long grow = (long)bm * BM + wm * 64 + m * 16 + kq * 4 + r;
        float v = acc[m][n][r] + bb;
        if constexpr (GELU) v = gelu_f(v);
        C[grow * ldc + gcol] = v;
      }
    }
  }
}

// ---------------------------------------------------------------------------
// Per-row top-4 (+5th for margin), softmax, mix components -> pts.
// One wave per row; tie-break = lower index (matches jax.lax.top_k).
// ---------------------------------------------------------------------------
__global__ __launch_bounds__(256) void topk_kernel(
    const float* __restrict__ logits, const float* __restrict__ comp,
    float* __restrict__ pts, int* __restrict__ rescueCnt, int* __restrict__ rescueList)
{
  int wid = threadIdx.x >> 6, lane = threadIdx.x & 63;
  long row = (long)blockIdx.x * 4 + wid;
  f32x4 v4 = *(const f32x4*)(logits + row * NC + lane * 4);
  float a[4] = {v4[0], v4[1], v4[2], v4[3]};

  float tv[5]; int ti[5];
#pragma unroll
  for (int t = 0; t < 5; ++t) {
    float lv = a[0]; int li = lane * 4;
#pragma unroll
    for (int i = 1; i < 4; ++i)
      if (a[i] > lv) { lv = a[i]; li = lane * 4 + i; }
#pragma unroll
    for (int off = 32; off >= 1; off >>= 1) {
      float ov = __shfl_xor(lv, off);
      int   oi = __shfl_xor(li, off);
      if (ov > lv || (ov == lv && oi < li)) { lv = ov; li = oi; }
    }
    tv[t] = lv; ti[t] = li;
    if (t < 4 && (li >> 2) == lane) a[li & 3] = -INFINITY;
  }

  float m = tv[0], w[4], s = 0.f;
#pragma unroll
  for (int t = 0; t < 4; ++t) { w[t] = expf(tv[t] - m); s += w[t]; }
  float inv = 1.0f / s;
  if (lane < 3) {
    float p = 0.f;
#pragma unroll
    for (int t = 0; t < 4; ++t) p += w[t] * inv * comp[ti[t] * 3 + lane];
    pts[row * 3 + lane] = p;
  }
  if (lane == 0 && (tv[3] - tv[4]) < TAU) {
    int pos = atomicAdd(rescueCnt, 1);
    rescueList[pos] = (int)row;
  }
}

// ---------------------------------------------------------------------------
// PARALLEL fp64 rescue, stage 1: partial dot products of layer 1.
// Grid = MAXR * 6 (channel chunks of 256) * 4 (K quarters of 512).
// ---------------------------------------------------------------------------
__global__ __launch_bounds__(256) void rescue_h1_kernel(
    const float* __restrict__ x, const float* __restrict__ embedMat,
    const int* __restrict__ liPtr, const float* __restrict__ W1,
    const int* __restrict__ cnt, const int* __restrict__ list,
    double* __restrict__ partial)
{
  int b = blockIdx.x;
  int s = b / 24, rem = b % 24;
  int cc = rem >> 2, kp = rem & 3;
  int n = *cnt;
  if (s >= n || s >= MAXR) return;
  int row = list[s];
  __shared__ double xd[512];
  int tid = threadIdx.x;
  int li = liPtr[0];
  int k0 = kp * 512;
  for (int j = tid; j < 512; j += 256)
    xd[j] = (double)x[(long)row * IN_DIM + k0 + j]
          + (double)embedMat[(long)li * IN_DIM + k0 + j];
  __syncthreads();
  int c = cc * 256 + tid;
  const float* wp = W1 + (long)k0 * HID + c;
  double s0 = 0, s1 = 0, s2 = 0, s3 = 0;
  for (int k = 0; k < 512; k += 4) {
    s0 += xd[k]     * (double)wp[(long)k * HID];
    s1 += xd[k + 1] * (double)wp[(long)(k + 1) * HID];
    s2 += xd[k + 2] * (double)wp[(long)(k + 2) * HID];
    s3 += xd[k + 3] * (double)wp[(long)(k + 3) * HID];
  }
  partial[((long)(s * 6 + cc) * 4 + kp) * 256 + tid] = (s0 + s1) + (s2 + s3);
}

// Stage 2: reduce K-quarters + bias + GELU (fp64). Grid = MAXR * 6.
__global__ __launch_bounds__(256) void rescue_h2_kernel(
    const float* __restrict__ b1, const int* __restrict__ cnt,
    const double* __restrict__ partial, double* __restrict__ hbuf)
{
  int b = blockIdx.x;
  int s = b / 6, cc = b % 6;
  int n = *cnt;
  if (s >= n || s >= MAXR) return;
  int tid = threadIdx.x;
  long base = ((long)(s * 6 + cc) * 4) * 256 + tid;
  double v = (double)b1[cc * 256 + tid]
           + ((partial[base] + partial[base + 256])
            + (partial[base + 512] + partial[base + 768]));
  hbuf[(long)s * HID + cc * 256 + tid]
      = 0.5 * v * (1.0 + erf(v * 0.70710678118654752440));
}

// Stage 3: fp64 logits + exact top-4 + softmax + mix. Grid = MAXR.
__global__ __launch_bounds__(256) void rescue_logits_kernel(
    const float* __restrict__ W2, const float* __restrict__ b2,
    const float* __restrict__ comp, const int* __restrict__ cnt,
    const int* __restrict__ list, const double* __restrict__ hbuf,
    float* __restrict__ pts)
{
  int s = blockIdx.x;
  int n = *cnt;
  if (s >= n || s >= MAXR) return;
  __shared__ double hd[HID];
  __shared__ double ld[NC];
  int tid = threadIdx.x;
  for (int j = tid; j < HID; j += 256) hd[j] = hbuf[(long)s * HID + j];
  __syncthreads();
  {
    const float* wp = W2 + tid;
    double a0 = 0, a1 = 0, a2 = 0, a3 = 0;
    for (int k = 0; k < HID; k += 4) {
      a0 += hd[k]     * (double)wp[(long)k * NC];
      a1 += hd[k + 1] * (double)wp[(long)(k + 1) * NC];
      a2 += hd[k + 2] * (double)wp[(long)(k + 2) * NC];
      a3 += hd[k + 3] * (double)wp[(long)(k + 3) * NC];
    }
    ld[tid] = (double)b2[tid] + ((a0 + a1) + (a2 + a3));
  }
  __syncthreads();
  if (tid == 0) {
    int row = list[s];
    int idx[4]; double val[4];
    unsigned long long mask[4] = {0, 0, 0, 0};
    for (int t = 0; t < 4; ++t) {
      double bv = -1e300; int bi = 0;
      for (int j = 0; j < NC; ++j) {
        if ((mask[j >> 6] >> (j & 63)) & 1ull) continue;
        if (ld[j] > bv) { bv = ld[j]; bi = j; }
      }
      idx[t] = bi; val[t] = bv; mask[bi >> 6] |= 1ull << (bi & 63);
    }
    double m = val[0], w[4], sum = 0;
    for (int t = 0; t < 4; ++t) { w[t] = exp(val[t] - m); sum += w[t]; }
    for (int c = 0; c < 3; ++c) {
      double p = 0;
      for (int t = 0; t < 4; ++t) p += (w[t] / sum) * (double)comp[idx[t] * 3 + c];
      pts[(long)row * 3 + c] = (float)p;
    }
  }
}

// ---------------------------------------------------------------------------
// Fallback: serial fp64 recompute for rescue slots >= MAXR (expected: none;
// exits immediately when n <= MAXR).
// ---------------------------------------------------------------------------
__global__ __launch_bounds__(256) void rescue_slow_kernel(
    const float* __restrict__ x, const float* __restrict__ embedMat,
    const int* __restrict__ liPtr, const float* __restrict__ W1,
    const float* __restrict__ b1, const float* __restrict__ W2,
    const float* __restrict__ b2, const float* __restrict__ comp,
    float* __restrict__ pts, const int* __restrict__ cnt, const int* __restrict__ list)
{
  __shared__ double xd[IN_DIM];
  __shared__ double hd[HID];
  __shared__ double ld[NC];
  int tid = threadIdx.x;
  int li = liPtr[0];
  int n = *cnt;
  for (int it = MAXR + blockIdx.x; it < n; it += gridDim.x) {
    int row = list[it];
    const float* xr = x + (long)row * IN_DIM;
    const float* er = embedMat + (long)li * IN_DIM;
    for (int j = tid; j < IN_DIM; j += 256)
      xd[j] = (double)xr[j] + (double)er[j];
    __syncthreads();
    for (int c = tid; c < HID; c += 256) {
      double s0 = 0, s1 = 0, s2 = 0, s3 = 0;
      const float* wp = W1 + c;
      for (int k = 0; k < IN_DIM; k += 4) {
        s0 += xd[k]     * (double)wp[(long)k * HID];
        s1 += xd[k + 1] * (double)wp[(long)(k + 1) * HID];
        s2 += xd[k + 2] * (double)wp[(long)(k + 2) * HID];
        s3 += xd[k + 3] * (double)wp[(long)(k + 3) * HID];
      }
      double s = (double)b1[c] + ((s0 + s1) + (s2 + s3));
      hd[c] = 0.5 * s * (1.0 + erf(s * 0.70710678118654752440));
    }
    __syncthreads();
    {
      int c = tid;
      double s0 = 0, s1 = 0, s2 = 0, s3 = 0;
      const float* wp = W2 + c;
      for (int k = 0; k < HID; k += 4) {
        s0 += hd[k]     * (double)wp[(long)k * NC];
        s1 += hd[k + 1] * (double)wp[(long)(k + 1) * NC];
        s2 += hd[k + 2] * (double)wp[(long)(k + 2) * NC];
        s3 += hd[k + 3] * (double)wp[(long)(k + 3) * NC];
      }
      ld[c] = (double)b2[c] + ((s0 + s1) + (s2 + s3));
    }
    __syncthreads();
    if (tid == 0) {
      int idx[4]; double val[4];
      unsigned long long mask[4] = {0, 0, 0, 0};
      for (int t = 0; t < 4; ++t) {
        double bv = -1e300; int bi = 0;
        for (int j = 0; j < NC; ++j) {
          if ((mask[j >> 6] >> (j & 63)) & 1ull) continue;
          if (ld[j] > bv) { bv = ld[j]; bi = j; }
        }
        idx[t] = bi; val[t] = bv; mask[bi >> 6] |= 1ull << (bi & 63);
      }
      double m = val[0], w[4], s = 0;
      for (int t = 0; t < 4; ++t) { w[t] = exp(val[t] - m); s += w[t]; }
      for (int c = 0; c < 3; ++c) {
        double p = 0;
        for (int t = 0; t < 4; ++t) p += (w[t] / s) * (double)comp[idx[t] * 3 + c];
        pts[(long)row * 3 + c] = (float)p;
      }
    }
    __syncthreads();
  }
}

// ---------------------------------------------------------------------------
// d = gelu(pts @ dec_w1 + dec_b1), stored bf16 (decoder GEMM A operand).
// ---------------------------------------------------------------------------
__global__ __launch_bounds__(256) void dec_a_kernel(
    const float* __restrict__ pts, const float* __restrict__ W1d,
    const float* __restrict__ b1d, unsigned short* __restrict__ dout)
{
  int  j = (blockIdx.x % 6) * 256 + threadIdx.x;
  long b = blockIdx.x / 6;
  const float* p = pts + b * 3;
  float s = fmaf(p[0], W1d[j], fmaf(p[1], W1d[HID + j], fmaf(p[2], W1d[2 * HID + j], b1d[j])));
  dout[b * HID + j] = f2bf(gelu_f(s));
}

// encoded output = components broadcast to (B, 256, 3)
__global__ __launch_bounds__(256) void enc_out_kernel(
    const float* __restrict__ comp, float* __restrict__ out)
{
  long base = (long)blockIdx.x * 768;
  int  t = threadIdx.x;
  out[base + t]       = comp[t];
  out[base + 256 + t] = comp[256 + t];
  out[base + 512 + t] = comp[512 + t];
}

__global__ void zero_cnt_kernel(int* c) { if (threadIdx.x == 0) *c = 0; }

// ---------------------------------------------------------------------------
extern "C" void kernel_launch(void* const* d_in, const int* in_sizes, int n_in,
                              void* d_out, int out_size, void* d_ws, size_t ws_size,
                              hipStream_t stream) {
  const float* x     = (const float*)d_in[0];
  const int*   liPtr = (const int*)  d_in[1];
  const float* embed = (const float*)d_in[2];
  const float* W1    = (const float*)d_in[3];
  const float* b1    = (const float*)d_in[4];
  const float* W2    = (const float*)d_in[5];
  const float* b2    = (const float*)d_in[6];
  const float* comp  = (const float*)d_in[7];
  const float* W1d   = (const float*)d_in[8];
  const float* b1d   = (const float*)d_in[9];
  const float* W2d   = (const float*)d_in[10];
  const float* b2d   = (const float*)d_in[11];
  float* out = (float*)d_out;

  char* w = (char*)d_ws;
  unsigned short* W1hT = (unsigned short*)(w);                      // 1536x2048 bf16
  unsigned short* W1lT = (unsigned short*)(w + 6291456);
  unsigned short* W2hT = (unsigned short*)(w + 12582912);           // 256x1536
  unsigned short* W2lT = (unsigned short*)(w + 13369344);
  unsigned short* W2dT = (unsigned short*)(w + 14155776);           // 2048x1536
  float* h      = (float*)(w + 20447232);                           // 16384x1536 f32
  float* logits = (float*)(w + 121110528);                          // 16384x256 f32
  float* pts    = (float*)(w + 137887744);                          // 16384x3
  int*   cnt    = (int*)  (w + 138084352);
  int*   list   = (int*)  (w + 138084608);
  // rescue scratch overlays the logits region (dead after topk):
  double* partial = (double*)(w + 121110528);                       // 64*6*4*256 f64 = 3MB
  double* hbuf    = (double*)(w + 124256256);                       // 64*1536 f64 = 768KB
  unsigned short* dbuf = (unsigned short*)h;                        // reuse h region

  zero_cnt_kernel<<<1, 64, 0, stream>>>(cnt);
  transpose_split_kernel<<<dim3(HID / 32, IN_DIM / 32), 256, 0, stream>>>(W1, IN_DIM, HID, W1hT, W1lT);
  transpose_split_kernel<<<dim3(NC / 32, HID / 32),     256, 0, stream>>>(W2, HID, NC, W2hT, W2lT);
  transpose_split_kernel<<<dim3(IN_DIM / 32, HID / 32), 256, 0, stream>>>(W2d, HID, IN_DIM, W2dT, nullptr);

  // enc1: h = gelu((x+embed) @ W1 + b1)   [split-bf16, fp32-class]
  gemm_kernel<true, true, true><<<(NB / 128) * (HID / 128), 256, 0, stream>>>(
      x, nullptr, IN_DIM, W1hT, W1lT, IN_DIM, b1, h, HID, IN_DIM, HID / 128, embed, liPtr);
  // enc2: logits = h @ W2 + b2            [split-bf16]
  gemm_kernel<true, false, false><<<(NB / 128) * (NC / 128), 256, 0, stream>>>(
      h, nullptr, HID, W2hT, W2lT, HID, b2, logits, NC, HID, NC / 128, nullptr, nullptr);

  topk_kernel<<<NB / 4, 256, 0, stream>>>(logits, comp, pts, cnt, list);

  // parallel fp64 rescue (expected n ~ 4 rows)
  rescue_h1_kernel<<<MAXR * 24, 256, 0, stream>>>(x, embed, liPtr, W1, cnt, list, partial);
  rescue_h2_kernel<<<MAXR * 6,  256, 0, stream>>>(b1, cnt, partial, hbuf);
  rescue_logits_kernel<<<MAXR,  256, 0, stream>>>(W2, b2, comp, cnt, list, hbuf, pts);
  rescue_slow_kernel<<<64, 256, 0, stream>>>(x, embed, liPtr, W1, b1, W2, b2, comp, pts, cnt, list);

  dec_a_kernel<<<NB * (HID / 256), 256, 0, stream>>>(pts, W1d, b1d, dbuf);
  // dec2: decoded = d @ W2d + b2d         [plain bf16]
  gemm_kernel<false, false, false><<<(NB / 128) * (IN_DIM / 128), 256, 0, stream>>>(
      nullptr, dbuf, HID, W2dT, nullptr, HID, b2d, out + ENC_ELEMS, IN_DIM, HID, IN_DIM / 128, nullptr, nullptr);

  enc_out_kernel<<<NB, 256, 0, stream>>>(comp, out);
}

// Round 3
// 816.763 us; speedup vs baseline: 2.2659x; 1.0335x over previous
//
#include <hip/hip_runtime.h>

// ---------------------------------------------------------------------------
// Autoencoder: x+embed -> Linear(2048,1536)+GELU -> Linear(1536,256) -> top4
//              -> softmax -> mix components(256,3) -> Linear(3,1536)+GELU
//              -> Linear(1536,2048).
// Round-3: encoder activations PRE-SPLIT into bf16 hi/lo (one BW-bound pass)
// instead of per-tile in-register split (VALU-bound 51%, 16-way LDS bank
// conflicts 5e7, MfmaUtil 29%). enc1 epilogue writes Hh/Hl directly so enc2's
// A is pre-split for free. fp64 rescue unchanged. Runtime ws_size check falls
// back to the round-2 path if the workspace is too small (needs 255.4 MB).
// ---------------------------------------------------------------------------

typedef float  f32x4  __attribute__((ext_vector_type(4)));
typedef short  short8 __attribute__((ext_vector_type(8)));

#define DEVINL __device__ __forceinline__

constexpr int  NB      = 16384;
constexpr int  IN_DIM  = 2048;
constexpr int  HID     = 1536;
constexpr int  NC      = 256;
constexpr long ENC_ELEMS = (long)NB * NC * 3;
constexpr float TAU = 2e-5f;
constexpr int  MAXR = 64;

DEVINL unsigned short f2bf(float f) {    // fp32 -> bf16 bits, RNE
  unsigned int u = __builtin_bit_cast(unsigned int, f);
  u = u + 0x7fffu + ((u >> 16) & 1u);
  return (unsigned short)(u >> 16);
}
DEVINL float bf2f(unsigned short h) {
  unsigned int u = ((unsigned int)h) << 16;
  return __builtin_bit_cast(float, u);
}
DEVINL float gelu_f(float v) {
  return 0.5f * v * (1.0f + erff(v * 0.70710678118654752440f));
}
DEVINL void llds16(const void* g, void* l) {   // async global->LDS, 16B/lane
  __builtin_amdgcn_global_load_lds(
      (const __attribute__((address_space(1))) void*)g,
      (__attribute__((address_space(3))) void*)l, 16, 0, 0);
}
DEVINL f32x4 mfma_bf16(short8 a, short8 b, f32x4 c) {
  return __builtin_amdgcn_mfma_f32_16x16x32_bf16(a, b, c, 0, 0, 0);
}

// ---------------------------------------------------------------------------
// Transpose (K,N) fp32 -> (N,K) bf16 hi (+ optional lo) for B operands.
// ---------------------------------------------------------------------------
__global__ __launch_bounds__(256) void transpose_split_kernel(
    const float* __restrict__ in, int K, int N,
    unsigned short* __restrict__ outH, unsigned short* __restrict__ outL)
{
  __shared__ float t[32][33];
  int tx = threadIdx.x & 31, ty = threadIdx.x >> 5;   // 32 x 8
  int n0 = blockIdx.x * 32, k0 = blockIdx.y * 32;
#pragma unroll
  for (int i = 0; i < 4; ++i)
    t[ty + i * 8][tx] = in[(long)(k0 + ty + i * 8) * N + n0 + tx];
  __syncthreads();
#pragma unroll
  for (int i = 0; i < 4; ++i) {
    float f = t[tx][ty + i * 8];
    long  o = (long)(n0 + ty + i * 8) * K + k0 + tx;
    unsigned short hb = f2bf(f);
    outH[o] = hb;
    if (outL) outL[o] = f2bf(f - bf2f(hb));
  }
}

// ---------------------------------------------------------------------------
// Pre-split pass: Xh/Xl = split(x + embed[li]), bf16 hi/lo. 8 elems/thread.
// ---------------------------------------------------------------------------
__global__ __launch_bounds__(256) void split_x_kernel(
    const float* __restrict__ x, const float* __restrict__ embedMat,
    const int* __restrict__ liPtr,
    unsigned short* __restrict__ Xh, unsigned short* __restrict__ Xl)
{
  long i = ((long)blockIdx.x * 256 + threadIdx.x) * 8;
  int  li = liPtr[0];
  int  col = (int)(i & (long)(IN_DIM - 1));
  const float* xr = x + i;
  const float* er = embedMat + (long)li * IN_DIM + col;
  f32x4 a0 = *(const f32x4*)(xr);
  f32x4 a1 = *(const f32x4*)(xr + 4);
  f32x4 e0 = *(const f32x4*)(er);
  f32x4 e1 = *(const f32x4*)(er + 4);
  short8 hv, lv;
#pragma unroll
  for (int j = 0; j < 4; ++j) {
    float f = a0[j] + e0[j];
    unsigned short hb = f2bf(f);
    hv[j] = (short)hb; lv[j] = (short)f2bf(f - bf2f(hb));
  }
#pragma unroll
  for (int j = 0; j < 4; ++j) {
    float f = a1[j] + e1[j];
    unsigned short hb = f2bf(f);
    hv[4 + j] = (short)hb; lv[4 + j] = (short)f2bf(f - bf2f(hb));
  }
  *(short8*)(Xh + i) = hv;
  *(short8*)(Xl + i) = lv;
}

// ---------------------------------------------------------------------------
// GEMM2: C[M,N] = act(A[M,K] * B^T[N,K] + bias), A/B pre-split bf16 hi/lo.
// 128x128x32 tile, 4 waves, 16x16x32 MFMA; SPLIT -> 3 MFMAs per frag pair.
// OUT_MODE: 0 = f32 C, 2 = bf16 hi/lo pair (Ch, Cl).
// ---------------------------------------------------------------------------
template<bool SPLIT, int OUT_MODE, bool GELU>
__global__ __launch_bounds__(256) void gemm2_kernel(
    const unsigned short* __restrict__ Ah, const unsigned short* __restrict__ Al, long lda,
    const unsigned short* __restrict__ Bh, const unsigned short* __restrict__ Bl, long ldb,
    const float* __restrict__ bias, float* __restrict__ Cf,
    unsigned short* __restrict__ Ch, unsigned short* __restrict__ Cl,
    long ldc, int K, int nbn)
{
  constexpr int BM = 128, BN = 128, BK = 32;
  __shared__ alignas(16) unsigned short sAh[BM * BK];
  __shared__ alignas(16) unsigned short sAl[SPLIT ? BM * BK : 8];
  __shared__ alignas(16) unsigned short sBh[BN * BK];
  __shared__ alignas(16) unsigned short sBl[SPLIT ? BN * BK : 8];
  __shared__ float sBias[BN];

  int tid = threadIdx.x;
  int nwg = gridDim.x, q = nwg >> 3, b0 = blockIdx.x;   // XCD swizzle (nwg%8==0)
  int sw = (b0 & 7) * q + (b0 >> 3);
  int bm = sw / nbn, bn = sw % nbn;

  if (tid < BN) sBias[tid] = bias[bn * BN + tid];

  int wid = tid >> 6, lane = tid & 63;
  int wm = wid >> 1, wn = wid & 1;
  int l15 = lane & 15, kq = lane >> 4;
  int koff = kq * 8;

  int rA = tid >> 2, cA = (tid & 3) * 8;

  f32x4 acc[4][4] = {};

  int nk = K / BK;
  for (int kt = 0; kt < nk; ++kt) {
    __syncthreads();
    {
      const unsigned short* gA = Ah + (long)(bm * BM + rA) * lda + kt * BK + cA;
#pragma unroll
      for (int j = 0; j < 2; ++j)
        llds16(gA + (long)(j * 64) * lda, (char*)sAh + j * 4096 + tid * 16);
    }
    if constexpr (SPLIT) {
      const unsigned short* gA = Al + (long)(bm * BM + rA) * lda + kt * BK + cA;
#pragma unroll
      for (int j = 0; j < 2; ++j)
        llds16(gA + (long)(j * 64) * lda, (char*)sAl + j * 4096 + tid * 16);
    }
    {
      const unsigned short* gB = Bh + (long)(bn * BN + rA) * ldb + kt * BK + cA;
#pragma unroll
      for (int j = 0; j < 2; ++j)
        llds16(gB + (long)(j * 64) * ldb, (char*)sBh + j * 4096 + tid * 16);
    }
    if constexpr (SPLIT) {
      const unsigned short* gB = Bl + (long)(bn * BN + rA) * ldb + kt * BK + cA;
#pragma unroll
      for (int j = 0; j < 2; ++j)
        llds16(gB + (long)(j * 64) * ldb, (char*)sBl + j * 4096 + tid * 16);
    }
    __syncthreads();

    short8 bh[4], bl[4];
#pragma unroll
    for (int n = 0; n < 4; ++n) {
      int col = wn * 64 + n * 16 + l15;
      bh[n] = *(const short8*)&sBh[col * BK + koff];
      if constexpr (SPLIT) bl[n] = *(const short8*)&sBl[col * BK + koff];
    }
#pragma unroll
    for (int m = 0; m < 4; ++m) {
      int row = wm * 64 + m * 16 + l15;
      short8 ah = *(const short8*)&sAh[row * BK + koff];
      short8 al;
      if constexpr (SPLIT) al = *(const short8*)&sAl[row * BK + koff];
#pragma unroll
      for (int n = 0; n < 4; ++n) {
        acc[m][n] = mfma_bf16(ah, bh[n], acc[m][n]);
        if constexpr (SPLIT) {
          acc[m][n] = mfma_bf16(al, bh[n], acc[m][n]);
          acc[m][n] = mfma_bf16(ah, bl[n], acc[m][n]);
        }
      }
    }
  }

  // epilogue: C/D layout col = lane&15, row = (lane>>4)*4 + r
#pragma unroll
  for (int m = 0; m < 4; ++m) {
#pragma unroll
    for (int n = 0; n < 4; ++n) {
      int  gcol = bn * BN + wn * 64 + n * 16 + l15;
      float bb  = sBias[wn * 64 + n * 16 + l15];
#pragma unroll
      for (int r = 0; r < 4; ++r) {
        long grow = (long)bm * BM + wm * 64 + m * 16 + kq * 4 + r;
        float v = acc[m][n][r] + bb;
        if constexpr (GELU) v = gelu_f(v);
        if constexpr (OUT_MODE == 0) {
          Cf[grow * ldc + gcol] = v;
        } else {
          unsigned short hb = f2bf(v);
          Ch[grow * ldc + gcol] = hb;
          Cl[grow * ldc + gcol] = f2bf(v - bf2f(hb));
        }
      }
    }
  }
}

// ---------------------------------------------------------------------------
// LEGACY GEMM (round-2 fallback): A staged f32, split in-register.
// ---------------------------------------------------------------------------
template<bool EMBED, bool GELU>
__global__ __launch_bounds__(256) void gemm_legacy_kernel(
    const float* __restrict__ Af, long lda,
    const unsigned short* __restrict__ BhT, const unsigned short* __restrict__ BlT,
    long ldb, const float* __restrict__ bias, float* __restrict__ C, long ldc,
    int K, int nbn, const float* __restrict__ embedMat, const int* __restrict__ liPtr)
{
  constexpr int BM = 128, BN = 128, BK = 32;
  __shared__ alignas(16) float          sAf[BM * BK];
  __shared__ alignas(16) unsigned short sBh[BN * BK];
  __shared__ alignas(16) unsigned short sBl[BN * BK];
  __shared__ alignas(16) float          sEmb[EMBED ? IN_DIM : 4];
  __shared__ float sBias[BN];

  int tid = threadIdx.x;
  int nwg = gridDim.x, q = nwg >> 3, b0 = blockIdx.x;
  int sw = (b0 & 7) * q + (b0 >> 3);
  int bm = sw / nbn, bn = sw % nbn;

  if constexpr (EMBED) {
    int li = liPtr[0];
    const f32x4* er = (const f32x4*)(embedMat + (long)li * IN_DIM);
    for (int i = tid; i < IN_DIM / 4; i += 256) ((f32x4*)sEmb)[i] = er[i];
  }
  if (tid < BN) sBias[tid] = bias[bn * BN + tid];

  int wid = tid >> 6, lane = tid & 63;
  int wm = wid >> 1, wn = wid & 1;
  int l15 = lane & 15, kq = lane >> 4;
  int koff = kq * 8;

  f32x4 acc[4][4] = {};

  int nk = K / BK;
  for (int kt = 0; kt < nk; ++kt) {
    __syncthreads();
    {
      const float* gA = Af + (long)(bm * BM + (tid >> 3)) * lda + kt * BK + (tid & 7) * 4;
#pragma unroll
      for (int j = 0; j < 4; ++j)
        llds16(gA + (long)(j * 32) * lda, (char*)sAf + j * 4096 + tid * 16);
    }
    {
      const unsigned short* gB = BhT + (long)(bn * BN + (tid >> 2)) * ldb + kt * BK + (tid & 3) * 8;
#pragma unroll
      for (int j = 0; j < 2; ++j)
        llds16(gB + (long)(j * 64) * ldb, (char*)sBh + j * 4096 + tid * 16);
    }
    {
      const unsigned short* gL = BlT + (long)(bn * BN + (tid >> 2)) * ldb + kt * BK + (tid & 3) * 8;
#pragma unroll
      for (int j = 0; j < 2; ++j)
        llds16(gL + (long)(j * 64) * ldb, (char*)sBl + j * 4096 + tid * 16);
    }
    __syncthreads();

    short8 bh[4], bl[4];
#pragma unroll
    for (int n = 0; n < 4; ++n) {
      int col = wn * 64 + n * 16 + l15;
      bh[n] = *(const short8*)&sBh[col * BK + koff];
      bl[n] = *(const short8*)&sBl[col * BK + koff];
    }

    float e[8];
    if constexpr (EMBED) {
#pragma unroll
      for (int i = 0; i < 8; ++i) e[i] = sEmb[kt * BK + koff + i];
    }
#pragma unroll
    for (int m = 0; m < 4; ++m) {
      int row = wm * 64 + m * 16 + l15;
      const float* ap = &sAf[row * BK + koff];
      short8 ah, al;
#pragma unroll
      for (int i = 0; i < 8; ++i) {
        float f = ap[i];
        if constexpr (EMBED) f += e[i];
        unsigned short hb = f2bf(f);
        float lo = f - bf2f(hb);
        ah[i] = (short)hb;
        al[i] = (short)f2bf(lo);
      }
#pragma unroll
      for (int n = 0; n < 4; ++n) {
        acc[m][n] = mfma_bf16(ah, bh[n], acc[m][n]);
        acc[m][n] = mfma_bf16(ah, bl[n], acc[m][n]);
        acc[m][n] = mfma_bf16(al, bh[n], acc[m][n]);
      }
    }
  }

#pragma unroll
  for (int m = 0; m < 4; ++m) {
#pragma unroll
    for (int n = 0; n < 4; ++n) {
      int  gcol = bn * BN + wn * 64 + n * 16 + l15;
      float bb  = sBias[wn * 64 + n * 16 + l15];
#pragma unroll
      for (int r = 0; r < 4; ++r) {
        long grow = (long)bm * BM + wm * 64 + m * 16 + kq * 4 + r;
        float v = acc[m][n][r] + bb;
        if constexpr (GELU) v = gelu_f(v);
        C[grow * ldc + gcol] = v;
      }
    }
  }
}

// ---------------------------------------------------------------------------
// Per-row top-4 (+5th for margin), softmax, mix components -> pts.
// ---------------------------------------------------------------------------
__global__ __launch_bounds__(256) void topk_kernel(
    const float* __restrict__ logits, const float* __restrict__ comp,
    float* __restrict__ pts, int* __restrict__ rescueCnt, int* __restrict__ rescueList)
{
  int wid = threadIdx.x >> 6, lane = threadIdx.x & 63;
  long row = (long)blockIdx.x * 4 + wid;
  f32x4 v4 = *(const f32x4*)(logits + row * NC + lane * 4);
  float a[4] = {v4[0], v4[1], v4[2], v4[3]};

  float tv[5]; int ti[5];
#pragma unroll
  for (int t = 0; t < 5; ++t) {
    float lv = a[0]; int li = lane * 4;
#pragma unroll
    for (int i = 1; i < 4; ++i)
      if (a[i] > lv) { lv = a[i]; li = lane * 4 + i; }
#pragma unroll
    for (int off = 32; off >= 1; off >>= 1) {
      float ov = __shfl_xor(lv, off);
      int   oi = __shfl_xor(li, off);
      if (ov > lv || (ov == lv && oi < li)) { lv = ov; li = oi; }
    }
    tv[t] = lv; ti[t] = li;
    if (t < 4 && (li >> 2) == lane) a[li & 3] = -INFINITY;
  }

  float m = tv[0], w[4], s = 0.f;
#pragma unroll
  for (int t = 0; t < 4; ++t) { w[t] = expf(tv[t] - m); s += w[t]; }
  float inv = 1.0f / s;
  if (lane < 3) {
    float p = 0.f;
#pragma unroll
    for (int t = 0; t < 4; ++t) p += w[t] * inv * comp[ti[t] * 3 + lane];
    pts[row * 3 + lane] = p;
  }
  if (lane == 0 && (tv[3] - tv[4]) < TAU) {
    int pos = atomicAdd(rescueCnt, 1);
    rescueList[pos] = (int)row;
  }
}

// ---------------------------------------------------------------------------
// PARALLEL fp64 rescue (3 stages) + serial fallback for n > MAXR.
// ---------------------------------------------------------------------------
__global__ __launch_bounds__(256) void rescue_h1_kernel(
    const float* __restrict__ x, const float* __restrict__ embedMat,
    const int* __restrict__ liPtr, const float* __restrict__ W1,
    const int* __restrict__ cnt, const int* __restrict__ list,
    double* __restrict__ partial)
{
  int b = blockIdx.x;
  int s = b / 24, rem = b % 24;
  int cc = rem >> 2, kp = rem & 3;
  int n = *cnt;
  if (s >= n || s >= MAXR) return;
  int row = list[s];
  __shared__ double xd[512];
  int tid = threadIdx.x;
  int li = liPtr[0];
  int k0 = kp * 512;
  for (int j = tid; j < 512; j += 256)
    xd[j] = (double)x[(long)row * IN_DIM + k0 + j]
          + (double)embedMat[(long)li * IN_DIM + k0 + j];
  __syncthreads();
  int c = cc * 256 + tid;
  const float* wp = W1 + (long)k0 * HID + c;
  double s0 = 0, s1 = 0, s2 = 0, s3 = 0;
  for (int k = 0; k < 512; k += 4) {
    s0 += xd[k]     * (double)wp[(long)k * HID];
    s1 += xd[k + 1] * (double)wp[(long)(k + 1) * HID];
    s2 += xd[k + 2] * (double)wp[(long)(k + 2) * HID];
    s3 += xd[k + 3] * (double)wp[(long)(k + 3) * HID];
  }
  partial[((long)(s * 6 + cc) * 4 + kp) * 256 + tid] = (s0 + s1) + (s2 + s3);
}

__global__ __launch_bounds__(256) void rescue_h2_kernel(
    const float* __restrict__ b1, const int* __restrict__ cnt,
    const double* __restrict__ partial, double* __restrict__ hbuf)
{
  int b = blockIdx.x;
  int s = b / 6, cc = b % 6;
  int n = *cnt;
  if (s >= n || s >= MAXR) return;
  int tid = threadIdx.x;
  long base = ((long)(s * 6 + cc) * 4) * 256 + tid;
  double v = (double)b1[cc * 256 + tid]
           + ((partial[base] + partial[base + 256])
            + (partial[base + 512] + partial[base + 768]));
  hbuf[(long)s * HID + cc * 256 + tid]
      = 0.5 * v * (1.0 + erf(v * 0.70710678118654752440));
}

__global__ __launch_bounds__(256) void rescue_logits_kernel(
    const float* __restrict__ W2, const float* __restrict__ b2,
    const float* __restrict__ comp, const int* __restrict__ cnt,
    const int* __restrict__ list, const double* __restrict__ hbuf,
    float* __restrict__ pts)
{
  int s = blockIdx.x;
  int n = *cnt;
  if (s >= n || s >= MAXR) return;
  __shared__ double hd[HID];
  __shared__ double ld[NC];
  int tid = threadIdx.x;
  for (int j = tid; j < HID; j += 256) hd[j] = hbuf[(long)s * HID + j];
  __syncthreads();
  {
    const float* wp = W2 + tid;
    double a0 = 0, a1 = 0, a2 = 0, a3 = 0;
    for (int k = 0; k < HID; k += 4) {
      a0 += hd[k]     * (double)wp[(long)k * NC];
      a1 += hd[k + 1] * (double)wp[(long)(k + 1) * NC];
      a2 += hd[k + 2] * (double)wp[(long)(k + 2) * NC];
      a3 += hd[k + 3] * (double)wp[(long)(k + 3) * NC];
    }
    ld[tid] = (double)b2[tid] + ((a0 + a1) + (a2 + a3));
  }
  __syncthreads();
  if (tid == 0) {
    int row = list[s];
    int idx[4]; double val[4];
    unsigned long long mask[4] = {0, 0, 0, 0};
    for (int t = 0; t < 4; ++t) {
      double bv = -1e300; int bi = 0;
      for (int j = 0; j < NC; ++j) {
        if ((mask[j >> 6] >> (j & 63)) & 1ull) continue;
        if (ld[j] > bv) { bv = ld[j]; bi = j; }
      }
      idx[t] = bi; val[t] = bv; mask[bi >> 6] |= 1ull << (bi & 63);
    }
    double m = val[0], w[4], sum = 0;
    for (int t = 0; t < 4; ++t) { w[t] = exp(val[t] - m); sum += w[t]; }
    for (int c = 0; c < 3; ++c) {
      double p = 0;
      for (int t = 0; t < 4; ++t) p += (w[t] / sum) * (double)comp[idx[t] * 3 + c];
      pts[(long)row * 3 + c] = (float)p;
    }
  }
}

__global__ __launch_bounds__(256) void rescue_slow_kernel(
    const float* __restrict__ x, const float* __restrict__ embedMat,
    const int* __restrict__ liPtr, const float* __restrict__ W1,
    const float* __restrict__ b1, const float* __restrict__ W2,
    const float* __restrict__ b2, const float* __restrict__ comp,
    float* __restrict__ pts, const int* __restrict__ cnt, const int* __restrict__ list)
{
  __shared__ double xd[IN_DIM];
  __shared__ double hd[HID];
  __shared__ double ld[NC];
  int tid = threadIdx.x;
  int li = liPtr[0];
  int n = *cnt;
  for (int it = MAXR + blockIdx.x; it < n; it += gridDim.x) {
    int row = list[it];
    const float* xr = x + (long)row * IN_DIM;
    const float* er = embedMat + (long)li * IN_DIM;
    for (int j = tid; j < IN_DIM; j += 256)
      xd[j] = (double)xr[j] + (double)er[j];
    __syncthreads();
    for (int c = tid; c < HID; c += 256) {
      double s0 = 0, s1 = 0, s2 = 0, s3 = 0;
      const float* wp = W1 + c;
      for (int k = 0; k < IN_DIM; k += 4) {
        s0 += xd[k]     * (double)wp[(long)k * HID];
        s1 += xd[k + 1] * (double)wp[(long)(k + 1) * HID];
        s2 += xd[k + 2] * (double)wp[(long)(k + 2) * HID];
        s3 += xd[k + 3] * (double)wp[(long)(k + 3) * HID];
      }
      double s = (double)b1[c] + ((s0 + s1) + (s2 + s3));
      hd[c] = 0.5 * s * (1.0 + erf(s * 0.70710678118654752440));
    }
    __syncthreads();
    {
      int c = tid;
      double s0 = 0, s1 = 0, s2 = 0, s3 = 0;
      const float* wp = W2 + c;
      for (int k = 0; k < HID; k += 4) {
        s0 += hd[k]     * (double)wp[(long)k * NC];
        s1 += hd[k + 1] * (double)wp[(long)(k + 1) * NC];
        s2 += hd[k + 2] * (double)wp[(long)(k + 2) * NC];
        s3 += hd[k + 3] * (double)wp[(long)(k + 3) * NC];
      }
      ld[c] = (double)b2[c] + ((s0 + s1) + (s2 + s3));
    }
    __syncthreads();
    if (tid == 0) {
      int idx[4]; double val[4];
      unsigned long long mask[4] = {0, 0, 0, 0};
      for (int t = 0; t < 4; ++t) {
        double bv = -1e300; int bi = 0;
        for (int j = 0; j < NC; ++j) {
          if ((mask[j >> 6] >> (j & 63)) & 1ull) continue;
          if (ld[j] > bv) { bv = ld[j]; bi = j; }
        }
        idx[t] = bi; val[t] = bv; mask[bi >> 6] |= 1ull << (bi & 63);
      }
      double m = val[0], w[4], s = 0;
      for (int t = 0; t < 4; ++t) { w[t] = exp(val[t] - m); s += w[t]; }
      for (int c = 0; c < 3; ++c) {
        double p = 0;
        for (int t = 0; t < 4; ++t) p += (w[t] / s) * (double)comp[idx[t] * 3 + c];
        pts[(long)row * 3 + c] = (float)p;
      }
    }
    __syncthreads();
  }
}

// ---------------------------------------------------------------------------
__global__ __launch_bounds__(256) void dec_a_kernel(
    const float* __restrict__ pts, const float* __restrict__ W1d,
    const float* __restrict__ b1d, unsigned short* __restrict__ dout)
{
  int  j = (blockIdx.x % 6) * 256 + threadIdx.x;
  long b = blockIdx.x / 6;
  const float* p = pts + b * 3;
  float s = fmaf(p[0], W1d[j], fmaf(p[1], W1d[HID + j], fmaf(p[2], W1d[2 * HID + j], b1d[j])));
  dout[b * HID + j] = f2bf(gelu_f(s));
}

__global__ __launch_bounds__(256) void enc_out_kernel(
    const float* __restrict__ comp, float* __restrict__ out)
{
  long base = (long)blockIdx.x * 768;
  int  t = threadIdx.x;
  out[base + t]       = comp[t];
  out[base + 256 + t] = comp[256 + t];
  out[base + 512 + t] = comp[512 + t];
}

__global__ void zero_cnt_kernel(int* c) { if (threadIdx.x == 0) *c = 0; }

// ---------------------------------------------------------------------------
extern "C" void kernel_launch(void* const* d_in, const int* in_sizes, int n_in,
                              void* d_out, int out_size, void* d_ws, size_t ws_size,
                              hipStream_t stream) {
  const float* x     = (const float*)d_in[0];
  const int*   liPtr = (const int*)  d_in[1];
  const float* embed = (const float*)d_in[2];
  const float* W1    = (const float*)d_in[3];
  const float* b1    = (const float*)d_in[4];
  const float* W2    = (const float*)d_in[5];
  const float* b2    = (const float*)d_in[6];
  const float* comp  = (const float*)d_in[7];
  const float* W1d   = (const float*)d_in[8];
  const float* b1d   = (const float*)d_in[9];
  const float* W2d   = (const float*)d_in[10];
  const float* b2d   = (const float*)d_in[11];
  float* out = (float*)d_out;

  char* w = (char*)d_ws;
  unsigned short* W1hT = (unsigned short*)(w);                      // 1536x2048 bf16
  unsigned short* W1lT = (unsigned short*)(w + 6291456);
  unsigned short* W2hT = (unsigned short*)(w + 12582912);           // 256x1536
  unsigned short* W2lT = (unsigned short*)(w + 13369344);
  unsigned short* W2dT = (unsigned short*)(w + 14155776);           // 2048x1536
  constexpr size_t A0 = 20447232;                                   // weights end
  constexpr size_t MAIN_WS = 255328256;

  transpose_split_kernel<<<dim3(HID / 32, IN_DIM / 32), 256, 0, stream>>>(W1, IN_DIM, HID, W1hT, W1lT);
  transpose_split_kernel<<<dim3(NC / 32, HID / 32),     256, 0, stream>>>(W2, HID, NC, W2hT, W2lT);
  transpose_split_kernel<<<dim3(IN_DIM / 32, HID / 32), 256, 0, stream>>>(W2d, HID, IN_DIM, W2dT, nullptr);

  if (ws_size >= MAIN_WS) {
    // -------- pre-split layout --------
    unsigned short* Xh = (unsigned short*)(w + A0);
    unsigned short* Xl = (unsigned short*)(w + A0 + 67108864);
    unsigned short* Hh = (unsigned short*)(w + A0 + 134217728);
    unsigned short* Hl = (unsigned short*)(w + A0 + 184549376);
    // overlays (X regions dead after enc1):
    float*  logits  = (float*)(w + A0);
    float*  pts     = (float*)(w + A0 + 16777216);
    int*    cnt     = (int*)  (w + A0 + 16973824);
    int*    list    = (int*)  (w + A0 + 16974080);
    double* partial = (double*)(w + A0 + 17108992);
    double* hbuf    = (double*)(w + A0 + 20254720);
    unsigned short* dbuf = Xl;

    split_x_kernel<<<NB * IN_DIM / 2048, 256, 0, stream>>>(x, embed, liPtr, Xh, Xl);

    // enc1: (Hh,Hl) = split(gelu((x+embed) @ W1 + b1))
    gemm2_kernel<true, 2, true><<<(NB / 128) * (HID / 128), 256, 0, stream>>>(
        Xh, Xl, IN_DIM, W1hT, W1lT, IN_DIM, b1, nullptr, Hh, Hl, HID, IN_DIM, HID / 128);
    // enc2: logits = h @ W2 + b2
    gemm2_kernel<true, 0, false><<<(NB / 128) * (NC / 128), 256, 0, stream>>>(
        Hh, Hl, HID, W2hT, W2lT, HID, b2, logits, nullptr, nullptr, NC, HID, NC / 128);

    zero_cnt_kernel<<<1, 64, 0, stream>>>(cnt);
    topk_kernel<<<NB / 4, 256, 0, stream>>>(logits, comp, pts, cnt, list);
    rescue_h1_kernel<<<MAXR * 24, 256, 0, stream>>>(x, embed, liPtr, W1, cnt, list, partial);
    rescue_h2_kernel<<<MAXR * 6,  256, 0, stream>>>(b1, cnt, partial, hbuf);
    rescue_logits_kernel<<<MAXR,  256, 0, stream>>>(W2, b2, comp, cnt, list, hbuf, pts);
    rescue_slow_kernel<<<64, 256, 0, stream>>>(x, embed, liPtr, W1, b1, W2, b2, comp, pts, cnt, list);

    dec_a_kernel<<<NB * (HID / 256), 256, 0, stream>>>(pts, W1d, b1d, dbuf);
    gemm2_kernel<false, 0, false><<<(NB / 128) * (IN_DIM / 128), 256, 0, stream>>>(
        dbuf, nullptr, HID, W2dT, nullptr, HID, b2d, out + ENC_ELEMS, nullptr, nullptr,
        IN_DIM, HID, IN_DIM / 128);
  } else {
    // -------- round-2 fallback layout --------
    float* h      = (float*)(w + A0);
    float* logits = (float*)(w + 121110528);
    float* pts    = (float*)(w + 137887744);
    int*   cnt    = (int*)  (w + 138084352);
    int*   list   = (int*)  (w + 138084608);
    double* partial = (double*)(w + 121110528);
    double* hbuf    = (double*)(w + 124256256);
    unsigned short* dbuf = (unsigned short*)h;

    gemm_legacy_kernel<true, true><<<(NB / 128) * (HID / 128), 256, 0, stream>>>(
        x, IN_DIM, W1hT, W1lT, IN_DIM, b1, h, HID, IN_DIM, HID / 128, embed, liPtr);
    gemm_legacy_kernel<false, false><<<(NB / 128) * (NC / 128), 256, 0, stream>>>(
        h, HID, W2hT, W2lT, HID, b2, logits, NC, HID, NC / 128, nullptr, nullptr);

    zero_cnt_kernel<<<1, 64, 0, stream>>>(cnt);
    topk_kernel<<<NB / 4, 256, 0, stream>>>(logits, comp, pts, cnt, list);
    rescue_h1_kernel<<<MAXR * 24, 256, 0, stream>>>(x, embed, liPtr, W1, cnt, list, partial);
    rescue_h2_kernel<<<MAXR * 6,  256, 0, stream>>>(b1, cnt, partial, hbuf);
    rescue_logits_kernel<<<MAXR,  256, 0, stream>>>(W2, b2, comp, cnt, list, hbuf, pts);
    rescue_slow_kernel<<<64, 256, 0, stream>>>(x, embed, liPtr, W1, b1, W2, b2, comp, pts, cnt, list);

    dec_a_kernel<<<NB * (HID / 256), 256, 0, stream>>>(pts, W1d, b1d, dbuf);
    gemm2_kernel<false, 0, false><<<(NB / 128) * (IN_DIM / 128), 256, 0, stream>>>(
        dbuf, nullptr, HID, W2dT, nullptr, HID, b2d, out + ENC_ELEMS, nullptr, nullptr,
        IN_DIM, HID, IN_DIM / 128);
  }

  enc_out_kernel<<<NB, 256, 0, stream>>>(comp, out);
}

// Round 4
// 799.597 us; speedup vs baseline: 2.3145x; 1.0215x over previous
//
#include <hip/hip_runtime.h>

// ---------------------------------------------------------------------------
// Autoencoder: x+embed -> Linear(2048,1536)+GELU -> Linear(1536,256) -> top4
//              -> softmax -> mix components(256,3) -> Linear(3,1536)+GELU
//              -> Linear(1536,2048).
// Round-4: ALL GEMM operands in packed pre-swizzled tile layout
//   tile(128 rows x 32 k) = 512 x 16B blocks, block(row,kq) stored at
//   slot = kq ^ ((row>>1)&3)  =>  elemOff = ((tile)*512 + row*4 + slot)*8.
// This makes global_load_lds staging fully contiguous AND ds_read_b128
// fragment reads ~2-way bank-conflict-free (was 8-way: 2.5e7 conflicts,
// MfmaUtil 39%). Encoder GEMMs split-bf16 (3-MFMA, fp32-class) so top-4
// selection matches fp32 reference; borderline rows (gap < TAU) recomputed
// exactly in fp64 (parallel 3-stage rescue). Decoder GEMM plain bf16.
// ---------------------------------------------------------------------------

typedef float  f32x4  __attribute__((ext_vector_type(4)));
typedef short  short8 __attribute__((ext_vector_type(8)));

#define DEVINL __device__ __forceinline__

constexpr int  NB      = 16384;
constexpr int  IN_DIM  = 2048;
constexpr int  HID     = 1536;
constexpr int  NC      = 256;
constexpr long ENC_ELEMS = (long)NB * NC * 3;
constexpr float TAU = 2e-5f;
constexpr int  MAXR = 64;
constexpr int  NKT1 = IN_DIM / 32;   // 64  (enc1 K-tiles)
constexpr int  NKT2 = HID / 32;      // 48  (enc2 / dec2 K-tiles)

DEVINL unsigned short f2bf(float f) {    // fp32 -> bf16 bits, RNE
  unsigned int u = __builtin_bit_cast(unsigned int, f);
  u = u + 0x7fffu + ((u >> 16) & 1u);
  return (unsigned short)(u >> 16);
}
DEVINL float bf2f(unsigned short h) {
  unsigned int u = ((unsigned int)h) << 16;
  return __builtin_bit_cast(float, u);
}
DEVINL float gelu_f(float v) {
  return 0.5f * v * (1.0f + erff(v * 0.70710678118654752440f));
}
DEVINL void llds16(const void* g, void* l) {   // async global->LDS, 16B/lane
  __builtin_amdgcn_global_load_lds(
      (const __attribute__((address_space(1))) void*)g,
      (__attribute__((address_space(3))) void*)l, 16, 0, 0);
}
DEVINL f32x4 mfma_bf16(short8 a, short8 b, f32x4 c) {
  return __builtin_amdgcn_mfma_f32_16x16x32_bf16(a, b, c, 0, 0, 0);
}
// packed-layout element offset for element (row-in-128-tile, k-in-32-chunk)
DEVINL long packed_off(long tileIdx, int rowp, int kq, int e) {
  int slot = kq ^ ((rowp >> 1) & 3);
  return (tileIdx * 512 + rowp * 4 + slot) * 8 + e;
}

// ---------------------------------------------------------------------------
// Transpose (K,N) fp32 -> packed-swizzled (N,K) bf16 hi (+ optional lo).
// Grid dim3(N/32, K/32). Threads ty<4 write hi blocks, ty>=4 write lo.
// ---------------------------------------------------------------------------
__global__ __launch_bounds__(256) void transpose_split_kernel(
    const float* __restrict__ in, int K, int N, int nkt,
    unsigned short* __restrict__ outH, unsigned short* __restrict__ outL)
{
  __shared__ float t[32][33];
  int tx = threadIdx.x & 31, ty = threadIdx.x >> 5;   // 32 x 8
  int n0 = blockIdx.x * 32, k0 = blockIdx.y * 32;
#pragma unroll
  for (int i = 0; i < 4; ++i)
    t[ty + i * 8][tx] = in[(long)(k0 + ty + i * 8) * N + n0 + tx];
  __syncthreads();

  int n = n0 + tx;
  int ntile = n >> 7, rowp = n & 127;
  int Kt = k0 >> 5;
  int j = ty & 3;                       // kq of this block
  long off = packed_off((long)ntile * nkt + Kt, rowp, j, 0);
  if (ty < 4) {
    short8 hv;
#pragma unroll
    for (int e = 0; e < 8; ++e) hv[e] = (short)f2bf(t[j * 8 + e][tx]);
    *(short8*)(outH + off) = hv;
  } else if (outL) {
    short8 lv;
#pragma unroll
    for (int e = 0; e < 8; ++e) {
      float f = t[j * 8 + e][tx];
      lv[e] = (short)f2bf(f - bf2f(f2bf(f)));
    }
    *(short8*)(outL + off) = lv;
  }
}

// ---------------------------------------------------------------------------
// Pre-split pass: Xh/Xl = split(x + embed[li]) in packed-swizzled layout.
// One thread = one 16B block (8 elems). Write address IS linear (g*8);
// the permutation is applied to the SOURCE read (rule: both-sides swizzle).
// ---------------------------------------------------------------------------
__global__ __launch_bounds__(256) void split_x_kernel(
    const float* __restrict__ x, const float* __restrict__ embedMat,
    const int* __restrict__ liPtr,
    unsigned short* __restrict__ Xh, unsigned short* __restrict__ Xl)
{
  long g = (long)blockIdx.x * 256 + threadIdx.x;      // block index
  int  li = liPtr[0];
  int  Mtile = (int)(g >> 15);                        // 64 Kt * 512 blocks
  int  rem = (int)(g & 32767);
  int  Kt = rem >> 9;
  int  b  = rem & 511;
  int  rowp = b >> 2, slot = b & 3;
  int  kq = slot ^ ((rowp >> 1) & 3);
  long grow = (long)Mtile * 128 + rowp;
  int  k = Kt * 32 + kq * 8;
  const float* xr = x + grow * IN_DIM + k;
  const float* er = embedMat + (long)li * IN_DIM + k;
  f32x4 a0 = *(const f32x4*)(xr);
  f32x4 a1 = *(const f32x4*)(xr + 4);
  f32x4 e0 = *(const f32x4*)(er);
  f32x4 e1 = *(const f32x4*)(er + 4);
  short8 hv, lv;
#pragma unroll
  for (int j2 = 0; j2 < 4; ++j2) {
    float f = a0[j2] + e0[j2];
    unsigned short hb = f2bf(f);
    hv[j2] = (short)hb; lv[j2] = (short)f2bf(f - bf2f(hb));
  }
#pragma unroll
  for (int j2 = 0; j2 < 4; ++j2) {
    float f = a1[j2] + e1[j2];
    unsigned short hb = f2bf(f);
    hv[4 + j2] = (short)hb; lv[4 + j2] = (short)f2bf(f - bf2f(hb));
  }
  *(short8*)(Xh + g * 8) = hv;
  *(short8*)(Xl + g * 8) = lv;
}

// ---------------------------------------------------------------------------
// GEMM: C[M,N] = act(A * B^T + bias); A,B packed-swizzled bf16 (hi/lo if
// SPLIT). 128x128x32 tile, 4 waves, 16x16x32 MFMA, 3 MFMAs/frag if SPLIT.
// OUT_MODE: 0 = f32 row-major C; 2 = packed-swizzled bf16 hi/lo (Ch/Cl,
// K-tiles = nktOut) for feeding the next GEMM's A operand.
// ---------------------------------------------------------------------------
template<bool SPLIT, int OUT_MODE, bool GELU>
__global__ __launch_bounds__(256) void gemm2_kernel(
    const unsigned short* __restrict__ Ah, const unsigned short* __restrict__ Al,
    const unsigned short* __restrict__ Bh, const unsigned short* __restrict__ Bl,
    int nkt, const float* __restrict__ bias, float* __restrict__ Cf,
    unsigned short* __restrict__ Ch, unsigned short* __restrict__ Cl,
    long ldc, int nktOut, int nbn)
{
  __shared__ alignas(16) unsigned short sAh[4096];
  __shared__ alignas(16) unsigned short sAl[SPLIT ? 4096 : 8];
  __shared__ alignas(16) unsigned short sBh[4096];
  __shared__ alignas(16) unsigned short sBl[SPLIT ? 4096 : 8];
  __shared__ float sBias[128];

  int tid = threadIdx.x;
  int nwg = gridDim.x, q = nwg >> 3, b0 = blockIdx.x;   // XCD swizzle (nwg%8==0)
  int sw = (b0 & 7) * q + (b0 >> 3);
  int bm = sw / nbn, bn = sw % nbn;

  if (tid < 128) sBias[tid] = bias[bn * 128 + tid];

  int wid = tid >> 6, lane = tid & 63;
  int wm = wid >> 1, wn = wid & 1;
  int l15 = lane & 15, kq = lane >> 4;

  f32x4 acc[4][4] = {};

  for (int kt = 0; kt < nkt; ++kt) {
    __syncthreads();
    {
      const char* gA = (const char*)Ah + ((long)(bm * nkt + kt)) * 8192 + tid * 16;
      llds16(gA,        (char*)sAh + tid * 16);
      llds16(gA + 4096, (char*)sAh + 4096 + tid * 16);
    }
    if constexpr (SPLIT) {
      const char* gA = (const char*)Al + ((long)(bm * nkt + kt)) * 8192 + tid * 16;
      llds16(gA,        (char*)sAl + tid * 16);
      llds16(gA + 4096, (char*)sAl + 4096 + tid * 16);
    }
    {
      const char* gB = (const char*)Bh + ((long)(bn * nkt + kt)) * 8192 + tid * 16;
      llds16(gB,        (char*)sBh + tid * 16);
      llds16(gB + 4096, (char*)sBh + 4096 + tid * 16);
    }
    if constexpr (SPLIT) {
      const char* gB = (const char*)Bl + ((long)(bn * nkt + kt)) * 8192 + tid * 16;
      llds16(gB,        (char*)sBl + tid * 16);
      llds16(gB + 4096, (char*)sBl + 4096 + tid * 16);
    }
    __syncthreads();

    short8 bh[4], bl[4];
#pragma unroll
    for (int n = 0; n < 4; ++n) {
      int rowp = wn * 64 + n * 16 + l15;
      int idx = (rowp * 4 + (kq ^ ((rowp >> 1) & 3))) * 8;
      bh[n] = *(const short8*)&sBh[idx];
      if constexpr (SPLIT) bl[n] = *(const short8*)&sBl[idx];
    }
#pragma unroll
    for (int m = 0; m < 4; ++m) {
      int rowp = wm * 64 + m * 16 + l15;
      int idx = (rowp * 4 + (kq ^ ((rowp >> 1) & 3))) * 8;
      short8 ah = *(const short8*)&sAh[idx];
      short8 al;
      if constexpr (SPLIT) al = *(const short8*)&sAl[idx];
#pragma unroll
      for (int n = 0; n < 4; ++n) {
        acc[m][n] = mfma_bf16(ah, bh[n], acc[m][n]);
        if constexpr (SPLIT) {
          acc[m][n] = mfma_bf16(al, bh[n], acc[m][n]);
          acc[m][n] = mfma_bf16(ah, bl[n], acc[m][n]);
        }
      }
    }
  }

  // epilogue: C/D layout col = lane&15, row = (lane>>4)*4 + r
#pragma unroll
  for (int m = 0; m < 4; ++m) {
#pragma unroll
    for (int n = 0; n < 4; ++n) {
      int  gcol = bn * 128 + wn * 64 + n * 16 + l15;
      float bb  = sBias[wn * 64 + n * 16 + l15];
#pragma unroll
      for (int r = 0; r < 4; ++r) {
        long grow = (long)bm * 128 + wm * 64 + m * 16 + kq * 4 + r;
        float v = acc[m][n][r] + bb;
        if constexpr (GELU) v = gelu_f(v);
        if constexpr (OUT_MODE == 0) {
          Cf[grow * ldc + gcol] = v;
        } else {
          // packed-swizzled store: (row=grow, k=gcol) of the NEXT GEMM's A
          int Mt = (int)(grow >> 7), rowpo = (int)(grow & 127);
          int Kt = gcol >> 5, kqo = (gcol >> 3) & 3, e = gcol & 7;
          long off = packed_off((long)Mt * nktOut + Kt, rowpo, kqo, e);
          unsigned short hb = f2bf(v);
          Ch[off] = hb;
          Cl[off] = f2bf(v - bf2f(hb));
        }
      }
    }
  }
}

// ---------------------------------------------------------------------------
// Per-row top-4 (+5th for margin), softmax, mix components -> pts.
// ---------------------------------------------------------------------------
__global__ __launch_bounds__(256) void topk_kernel(
    const float* __restrict__ logits, const float* __restrict__ comp,
    float* __restrict__ pts, int* __restrict__ rescueCnt, int* __restrict__ rescueList)
{
  int wid = threadIdx.x >> 6, lane = threadIdx.x & 63;
  long row = (long)blockIdx.x * 4 + wid;
  f32x4 v4 = *(const f32x4*)(logits + row * NC + lane * 4);
  float a[4] = {v4[0], v4[1], v4[2], v4[3]};

  float tv[5]; int ti[5];
#pragma unroll
  for (int t = 0; t < 5; ++t) {
    float lv = a[0]; int li = lane * 4;
#pragma unroll
    for (int i = 1; i < 4; ++i)
      if (a[i] > lv) { lv = a[i]; li = lane * 4 + i; }
#pragma unroll
    for (int off = 32; off >= 1; off >>= 1) {
      float ov = __shfl_xor(lv, off);
      int   oi = __shfl_xor(li, off);
      if (ov > lv || (ov == lv && oi < li)) { lv = ov; li = oi; }
    }
    tv[t] = lv; ti[t] = li;
    if (t < 4 && (li >> 2) == lane) a[li & 3] = -INFINITY;
  }

  float m = tv[0], w[4], s = 0.f;
#pragma unroll
  for (int t = 0; t < 4; ++t) { w[t] = expf(tv[t] - m); s += w[t]; }
  float inv = 1.0f / s;
  if (lane < 3) {
    float p = 0.f;
#pragma unroll
    for (int t = 0; t < 4; ++t) p += w[t] * inv * comp[ti[t] * 3 + lane];
    pts[row * 3 + lane] = p;
  }
  if (lane == 0 && (tv[3] - tv[4]) < TAU) {
    int pos = atomicAdd(rescueCnt, 1);
    rescueList[pos] = (int)row;
  }
}

// ---------------------------------------------------------------------------
// PARALLEL fp64 rescue (3 stages) + serial fallback for n > MAXR.
// ---------------------------------------------------------------------------
__global__ __launch_bounds__(256) void rescue_h1_kernel(
    const float* __restrict__ x, const float* __restrict__ embedMat,
    const int* __restrict__ liPtr, const float* __restrict__ W1,
    const int* __restrict__ cnt, const int* __restrict__ list,
    double* __restrict__ partial)
{
  int b = blockIdx.x;
  int s = b / 24, rem = b % 24;
  int cc = rem >> 2, kp = rem & 3;
  int n = *cnt;
  if (s >= n || s >= MAXR) return;
  int row = list[s];
  __shared__ double xd[512];
  int tid = threadIdx.x;
  int li = liPtr[0];
  int k0 = kp * 512;
  for (int j = tid; j < 512; j += 256)
    xd[j] = (double)x[(long)row * IN_DIM + k0 + j]
          + (double)embedMat[(long)li * IN_DIM + k0 + j];
  __syncthreads();
  int c = cc * 256 + tid;
  const float* wp = W1 + (long)k0 * HID + c;
  double s0 = 0, s1 = 0, s2 = 0, s3 = 0;
  for (int k = 0; k < 512; k += 4) {
    s0 += xd[k]     * (double)wp[(long)k * HID];
    s1 += xd[k + 1] * (double)wp[(long)(k + 1) * HID];
    s2 += xd[k + 2] * (double)wp[(long)(k + 2) * HID];
    s3 += xd[k + 3] * (double)wp[(long)(k + 3) * HID];
  }
  partial[((long)(s * 6 + cc) * 4 + kp) * 256 + tid] = (s0 + s1) + (s2 + s3);
}

__global__ __launch_bounds__(256) void rescue_h2_kernel(
    const float* __restrict__ b1, const int* __restrict__ cnt,
    const double* __restrict__ partial, double* __restrict__ hbuf)
{
  int b = blockIdx.x;
  int s = b / 6, cc = b % 6;
  int n = *cnt;
  if (s >= n || s >= MAXR) return;
  int tid = threadIdx.x;
  long base = ((long)(s * 6 + cc) * 4) * 256 + tid;
  double v = (double)b1[cc * 256 + tid]
           + ((partial[base] + partial[base + 256])
            + (partial[base + 512] + partial[base + 768]));
  hbuf[(long)s * HID + cc * 256 + tid]
      = 0.5 * v * (1.0 + erf(v * 0.70710678118654752440));
}

__global__ __launch_bounds__(256) void rescue_logits_kernel(
    const float* __restrict__ W2, const float* __restrict__ b2,
    const float* __restrict__ comp, const int* __restrict__ cnt,
    const int* __restrict__ list, const double* __restrict__ hbuf,
    float* __restrict__ pts)
{
  int s = blockIdx.x;
  int n = *cnt;
  if (s >= n || s >= MAXR) return;
  __shared__ double hd[HID];
  __shared__ double ld[NC];
  int tid = threadIdx.x;
  for (int j = tid; j < HID; j += 256) hd[j] = hbuf[(long)s * HID + j];
  __syncthreads();
  {
    const float* wp = W2 + tid;
    double a0 = 0, a1 = 0, a2 = 0, a3 = 0;
    for (int k = 0; k < HID; k += 4) {
      a0 += hd[k]     * (double)wp[(long)k * NC];
      a1 += hd[k + 1] * (double)wp[(long)(k + 1) * NC];
      a2 += hd[k + 2] * (double)wp[(long)(k + 2) * NC];
      a3 += hd[k + 3] * (double)wp[(long)(k + 3) * NC];
    }
    ld[tid] = (double)b2[tid] + ((a0 + a1) + (a2 + a3));
  }
  __syncthreads();
  if (tid == 0) {
    int row = list[s];
    int idx[4]; double val[4];
    unsigned long long mask[4] = {0, 0, 0, 0};
    for (int t = 0; t < 4; ++t) {
      double bv = -1e300; int bi = 0;
      for (int j = 0; j < NC; ++j) {
        if ((mask[j >> 6] >> (j & 63)) & 1ull) continue;
        if (ld[j] > bv) { bv = ld[j]; bi = j; }
      }
      idx[t] = bi; val[t] = bv; mask[bi >> 6] |= 1ull << (bi & 63);
    }
    double m = val[0], w[4], sum = 0;
    for (int t = 0; t < 4; ++t) { w[t] = exp(val[t] - m); sum += w[t]; }
    for (int c = 0; c < 3; ++c) {
      double p = 0;
      for (int t = 0; t < 4; ++t) p += (w[t] / sum) * (double)comp[idx[t] * 3 + c];
      pts[(long)row * 3 + c] = (float)p;
    }
  }
}

__global__ __launch_bounds__(256) void rescue_slow_kernel(
    const float* __restrict__ x, const float* __restrict__ embedMat,
    const int* __restrict__ liPtr, const float* __restrict__ W1,
    const float* __restrict__ b1, const float* __restrict__ W2,
    const float* __restrict__ b2, const float* __restrict__ comp,
    float* __restrict__ pts, const int* __restrict__ cnt, const int* __restrict__ list)
{
  __shared__ double xd[IN_DIM];
  __shared__ double hd[HID];
  __shared__ double ld[NC];
  int tid = threadIdx.x;
  int li = liPtr[0];
  int n = *cnt;
  for (int it = MAXR + blockIdx.x; it < n; it += gridDim.x) {
    int row = list[it];
    const float* xr = x + (long)row * IN_DIM;
    const float* er = embedMat + (long)li * IN_DIM;
    for (int j = tid; j < IN_DIM; j += 256)
      xd[j] = (double)xr[j] + (double)er[j];
    __syncthreads();
    for (int c = tid; c < HID; c += 256) {
      double s0 = 0, s1 = 0, s2 = 0, s3 = 0;
      const float* wp = W1 + c;
      for (int k = 0; k < IN_DIM; k += 4) {
        s0 += xd[k]     * (double)wp[(long)k * HID];
        s1 += xd[k + 1] * (double)wp[(long)(k + 1) * HID];
        s2 += xd[k + 2] * (double)wp[(long)(k + 2) * HID];
        s3 += xd[k + 3] * (double)wp[(long)(k + 3) * HID];
      }
      double s = (double)b1[c] + ((s0 + s1) + (s2 + s3));
      hd[c] = 0.5 * s * (1.0 + erf(s * 0.70710678118654752440));
    }
    __syncthreads();
    {
      int c = tid;
      double s0 = 0, s1 = 0, s2 = 0, s3 = 0;
      const float* wp = W2 + c;
      for (int k = 0; k < HID; k += 4) {
        s0 += hd[k]     * (double)wp[(long)k * NC];
        s1 += hd[k + 1] * (double)wp[(long)(k + 1) * NC];
        s2 += hd[k + 2] * (double)wp[(long)(k + 2) * NC];
        s3 += hd[k + 3] * (double)wp[(long)(k + 3) * NC];
      }
      ld[c] = (double)b2[c] + ((s0 + s1) + (s2 + s3));
    }
    __syncthreads();
    if (tid == 0) {
      int idx[4]; double val[4];
      unsigned long long mask[4] = {0, 0, 0, 0};
      for (int t = 0; t < 4; ++t) {
        double bv = -1e300; int bi = 0;
        for (int j = 0; j < NC; ++j) {
          if ((mask[j >> 6] >> (j & 63)) & 1ull) continue;
          if (ld[j] > bv) { bv = ld[j]; bi = j; }
        }
        idx[t] = bi; val[t] = bv; mask[bi >> 6] |= 1ull << (bi & 63);
      }
      double m = val[0], w[4], s = 0;
      for (int t = 0; t < 4; ++t) { w[t] = exp(val[t] - m); s += w[t]; }
      for (int c = 0; c < 3; ++c) {
        double p = 0;
        for (int t = 0; t < 4; ++t) p += (w[t] / s) * (double)comp[idx[t] * 3 + c];
        pts[(long)row * 3 + c] = (float)p;
      }
    }
    __syncthreads();
  }
}

// ---------------------------------------------------------------------------
// d = gelu(pts @ dec_w1 + dec_b1), stored packed-swizzled bf16 (dec2's A).
// ---------------------------------------------------------------------------
__global__ __launch_bounds__(256) void dec_a_kernel(
    const float* __restrict__ pts, const float* __restrict__ W1d,
    const float* __restrict__ b1d, unsigned short* __restrict__ dout)
{
  int  j = (blockIdx.x % 6) * 256 + threadIdx.x;
  long b = blockIdx.x / 6;
  const float* p = pts + b * 3;
  float s = fmaf(p[0], W1d[j], fmaf(p[1], W1d[HID + j], fmaf(p[2], W1d[2 * HID + j], b1d[j])));
  int Mt = (int)(b >> 7), rowp = (int)(b & 127);
  int Kt = j >> 5, kq = (j >> 3) & 3, e = j & 7;
  dout[packed_off((long)Mt * NKT2 + Kt, rowp, kq, e)] = f2bf(gelu_f(s));
}

__global__ __launch_bounds__(256) void enc_out_kernel(
    const float* __restrict__ comp, float* __restrict__ out)
{
  long base = (long)blockIdx.x * 768;
  int  t = threadIdx.x;
  out[base + t]       = comp[t];
  out[base + 256 + t] = comp[256 + t];
  out[base + 512 + t] = comp[512 + t];
}

__global__ void zero_cnt_kernel(int* c) { if (threadIdx.x == 0) *c = 0; }

// ---------------------------------------------------------------------------
extern "C" void kernel_launch(void* const* d_in, const int* in_sizes, int n_in,
                              void* d_out, int out_size, void* d_ws, size_t ws_size,
                              hipStream_t stream) {
  const float* x     = (const float*)d_in[0];
  const int*   liPtr = (const int*)  d_in[1];
  const float* embed = (const float*)d_in[2];
  const float* W1    = (const float*)d_in[3];
  const float* b1    = (const float*)d_in[4];
  const float* W2    = (const float*)d_in[5];
  const float* b2    = (const float*)d_in[6];
  const float* comp  = (const float*)d_in[7];
  const float* W1d   = (const float*)d_in[8];
  const float* b1d   = (const float*)d_in[9];
  const float* W2d   = (const float*)d_in[10];
  const float* b2d   = (const float*)d_in[11];
  float* out = (float*)d_out;

  char* w = (char*)d_ws;
  unsigned short* W1hT = (unsigned short*)(w);                      // packed 12x64 tiles
  unsigned short* W1lT = (unsigned short*)(w + 6291456);
  unsigned short* W2hT = (unsigned short*)(w + 12582912);           // packed 2x48
  unsigned short* W2lT = (unsigned short*)(w + 13369344);
  unsigned short* W2dT = (unsigned short*)(w + 14155776);           // packed 16x48
  constexpr size_t A0 = 20447232;                                   // weights end

  unsigned short* Xh = (unsigned short*)(w + A0);                   // packed 128x64
  unsigned short* Xl = (unsigned short*)(w + A0 + 67108864);
  unsigned short* Hh = (unsigned short*)(w + A0 + 134217728);       // packed 128x48
  unsigned short* Hl = (unsigned short*)(w + A0 + 184549376);
  // overlays (X regions dead after enc1):
  float*  logits  = (float*)(w + A0);
  float*  pts     = (float*)(w + A0 + 16777216);
  int*    cnt     = (int*)  (w + A0 + 16973824);
  int*    list    = (int*)  (w + A0 + 16974080);
  double* partial = (double*)(w + A0 + 17108992);
  double* hbuf    = (double*)(w + A0 + 20254720);
  unsigned short* dbuf = Xl;                                        // Xl dead after enc1

  transpose_split_kernel<<<dim3(HID / 32, IN_DIM / 32), 256, 0, stream>>>(W1, IN_DIM, HID, NKT1, W1hT, W1lT);
  transpose_split_kernel<<<dim3(NC / 32, HID / 32),     256, 0, stream>>>(W2, HID, NC, NKT2, W2hT, W2lT);
  transpose_split_kernel<<<dim3(IN_DIM / 32, HID / 32), 256, 0, stream>>>(W2d, HID, IN_DIM, NKT2, W2dT, nullptr);

  split_x_kernel<<<NB * IN_DIM / 2048, 256, 0, stream>>>(x, embed, liPtr, Xh, Xl);

  // enc1: (Hh,Hl) = split(gelu((x+embed) @ W1 + b1))   [split-bf16 -> packed out]
  gemm2_kernel<true, 2, true><<<(NB / 128) * (HID / 128), 256, 0, stream>>>(
      Xh, Xl, W1hT, W1lT, NKT1, b1, nullptr, Hh, Hl, 0, NKT2, HID / 128);
  // enc2: logits = h @ W2 + b2                          [split-bf16 -> f32]
  gemm2_kernel<true, 0, false><<<(NB / 128) * (NC / 128), 256, 0, stream>>>(
      Hh, Hl, W2hT, W2lT, NKT2, b2, logits, nullptr, nullptr, NC, 0, NC / 128);

  zero_cnt_kernel<<<1, 64, 0, stream>>>(cnt);
  topk_kernel<<<NB / 4, 256, 0, stream>>>(logits, comp, pts, cnt, list);
  rescue_h1_kernel<<<MAXR * 24, 256, 0, stream>>>(x, embed, liPtr, W1, cnt, list, partial);
  rescue_h2_kernel<<<MAXR * 6,  256, 0, stream>>>(b1, cnt, partial, hbuf);
  rescue_logits_kernel<<<MAXR,  256, 0, stream>>>(W2, b2, comp, cnt, list, hbuf, pts);
  rescue_slow_kernel<<<64, 256, 0, stream>>>(x, embed, liPtr, W1, b1, W2, b2, comp, pts, cnt, list);

  dec_a_kernel<<<NB * (HID / 256), 256, 0, stream>>>(pts, W1d, b1d, dbuf);
  // dec2: decoded = d @ W2d + b2d                       [plain bf16 -> f32 out]
  gemm2_kernel<false, 0, false><<<(NB / 128) * (IN_DIM / 128), 256, 0, stream>>>(
      dbuf, nullptr, W2dT, nullptr, NKT2, b2d, out + ENC_ELEMS, nullptr, nullptr,
      IN_DIM, 0, IN_DIM / 128);

  enc_out_kernel<<<NB, 256, 0, stream>>>(comp, out);
}